// Round 6
// baseline (1637.435 us; speedup 1.0000x reference)
//
#include <hip/hip_runtime.h>

#define N_NODES 50000
#define R_REL   4
#define E_NNZ   800000
#define ED_EDGES 200000
#define H_DIM   128
#define L_DIM   64

#define RN_TOTAL (R_REL * N_NODES)    // 200000
#define ETOT     (R_REL * E_NNZ)      // 3,200,000

// ----- radix CSR-build constants -----
#define EPB   8192                    // edges per radix block
#define NB    391                     // ceil(ETOT/EPB)
#define RBK   196                     // row buckets per relation (256 rows each)
#define KBK   (R_REL * RBK)           // 784 total buckets
#define HTOT  (KBK * NB)              // 306,544 histogram entries
#define SCB   300                     // ceil(HTOT/1024) scan blocks
#define MAXB  6144                    // LDS edge capacity per bucket

// ---------------- workspace layout (bytes); budget <= 213,601,536 ----------
#define WS_RP    0u            // (RN+1) int -> 800,256
#define WS_HIST  800256u       // HTOT int -> 2,026,496 (pad)
#define WS_BSUM  2026496u      // 1024 int -> 2,030,592
#define WS_CV    2030592u      // ETOT int2 = 25.6e6 -> 27,630,592   (final cse, persistent)
#define WS_TMP   27630720u     // ETOT int2 = 25.6e6 -> 53,230,720   (bucketed tmp; later h_n)
#define WS_XALL  53230720u     // N*192 ushort = 19.2e6 -> 72,430,720 (later Ys_p)
#define WS_SP    72430720u     // N*248 f32 = 49.6e6 -> 122,030,720  (later h_f, Ys_f, za/zb)
#define WS_SF    122030720u    // N*148 f32 = 29.6e6 -> 151,630,720  (later Yr_p)
#define WS_SN    151630720u    // N*148 f32 = 29.6e6 -> 181,230,720  (later Yr_f)
#define WS_HPR   181230720u    // N*128 f32 = 25.6e6 -> 206,830,720  (h_p; later Ys_n, z)
#define WS_HN    WS_TMP                    // h_n reuses tmp (dead after bucket_sort)
#define WS_HF    WS_SP                     // h_f reuses S_p (dead after gemm1_p)
#define WS_YSP   WS_XALL                   // 12.8e6 (xall dead after spmm1)
#define WS_YSF   (WS_SP + 25600000u)       // 98,030,720 (S_p tail)
#define WS_YRP   WS_SF                     // 25.6e6 (S_f dead after gemm1_f)
#define WS_YRF   WS_SN                     // 25.6e6 (S_n dead after gemm1_n)
#define WS_YSN   WS_HPR                    // 12.8e6 (h_p dead after gemm2_p)
#define WS_YRN   WS_HF                     // 25.6e6 (h_f dead after gemm2_f)
#define WS_Z     194030720u                // 12.8e6 -> 206,830,720 (h_p tail)
#define WS_ZA    WS_SP                     // N*64 f32 (S_p/h_f dead after spmm2z)
#define WS_ZB    (WS_SP + 12800000u)       // N*64 f32 -> ends 98,030,720

__device__ __forceinline__ ushort f2bf(float f) {
    unsigned u = __float_as_uint(f);
    unsigned r = (u + 0x7fffu + ((u >> 16) & 1u)) >> 16;   // RNE
    return (ushort)r;
}
__device__ __forceinline__ float bf2f(ushort u) {
    return __uint_as_float(((unsigned)u) << 16);
}

// ---------------- bf16 staging: one merged 384B-stride table ----------------
__global__ void cast_xall_kernel(const float* __restrict__ xp, const float* __restrict__ xf,
                                 const float* __restrict__ xn, ushort* __restrict__ xall) {
    int i = blockIdx.x * 256 + threadIdx.x;
    if (i >= N_NODES * 192) return;
    int node = i / 192, k = i - node * 192;
    float v = 0.f;
    if (k < 62) v = xp[node * 62 + k];
    else if (k >= 64 && k < 138) {
        int j = k - 64, d = j >> 1;
        v = (j & 1) ? xn[node * 37 + d] : xf[node * 37 + d];
    }
    xall[i] = f2bf(v);
}

// ---------------- radix CSR build ----------------
__global__ void radix_hist_kernel(const int* __restrict__ rows, int* __restrict__ H) {
    __shared__ int hist[KBK];
    int blk = blockIdx.x, t = threadIdx.x;
    for (int i = t; i < KBK; i += 256) hist[i] = 0;
    __syncthreads();
    int base = blk * EPB;
    #pragma unroll 1
    for (int i = 0; i < EPB / 256; i++) {
        int g = base + i * 256 + t;
        if (g < ETOT) {
            int r = g / E_NNZ;
            atomicAdd(&hist[r * RBK + (rows[g] >> 8)], 1);
        }
    }
    __syncthreads();
    for (int i = t; i < KBK; i += 256) H[i * NB + blk] = hist[i];
}

__global__ void scan_part_kernel(const int* __restrict__ H, int* __restrict__ bsum) {
    __shared__ int red[256];
    int base = blockIdx.x * 1024, t = threadIdx.x;
    int s = 0;
    #pragma unroll
    for (int i = 0; i < 4; i++) {
        int idx = base + i * 256 + t;
        if (idx < HTOT) s += H[idx];
    }
    red[t] = s; __syncthreads();
    for (int d = 128; d > 0; d >>= 1) {
        if (t < d) red[t] += red[t + d];
        __syncthreads();
    }
    if (t == 0) bsum[blockIdx.x] = red[0];
}

__global__ void scan_bsum_kernel(int* __restrict__ bsum, int* __restrict__ rp) {
    __shared__ int sh[512];
    int t = threadIdx.x;
    int v = (t < SCB) ? bsum[t] : 0;
    sh[t] = v; __syncthreads();
    for (int d = 1; d < 512; d <<= 1) {
        int u = (t >= d) ? sh[t - d] : 0;
        __syncthreads();
        sh[t] += u;
        __syncthreads();
    }
    if (t < SCB) bsum[t] = sh[t] - v;
    if (t == 0) rp[RN_TOTAL] = ETOT;
}

__global__ void scan_final_kernel(int* __restrict__ H, const int* __restrict__ bsum) {
    __shared__ int sh[256];
    int base = blockIdx.x * 1024, t = threadIdx.x;
    int c[4]; int s = 0;
    #pragma unroll
    for (int i = 0; i < 4; i++) {
        int idx = base + t * 4 + i;
        c[i] = (idx < HTOT) ? H[idx] : 0;
        s += c[i];
    }
    sh[t] = s; __syncthreads();
    for (int d = 1; d < 256; d <<= 1) {
        int u = (t >= d) ? sh[t - d] : 0;
        __syncthreads();
        sh[t] += u;
        __syncthreads();
    }
    int off = bsum[blockIdx.x] + sh[t] - s;
    #pragma unroll
    for (int i = 0; i < 4; i++) {
        int idx = base + t * 4 + i;
        if (idx < HTOT) H[idx] = off;
        off += c[i];
    }
}

__global__ void radix_scatter_kernel(const int* __restrict__ rows, const int* __restrict__ cols,
                                     const float* __restrict__ vals, const int* __restrict__ H,
                                     int2* __restrict__ tmp) {
    __shared__ int cur[KBK];
    int blk = blockIdx.x, t = threadIdx.x;
    for (int i = t; i < KBK; i += 256) cur[i] = H[i * NB + blk];
    __syncthreads();
    int base = blk * EPB;
    #pragma unroll 1
    for (int i = 0; i < EPB / 256; i++) {
        int g = base + i * 256 + t;
        if (g < ETOT) {
            int r = g / E_NNZ;
            int row = rows[g];
            int b = r * RBK + (row >> 8);
            int p = atomicAdd(&cur[b], 1);
            tmp[p] = make_int2(cols[g] | ((row & 255) << 16), __float_as_int(vals[g]));
        }
    }
}

__launch_bounds__(256)
__global__ void bucket_sort_kernel(const int2* __restrict__ tmp, const int* __restrict__ H,
                                   int* __restrict__ rp, int2* __restrict__ cse) {
    __shared__ int hist[256];
    __shared__ int sc[256];
    __shared__ int cur[256];
    __shared__ int2 eb[MAXB];
    int b = blockIdx.x, t = threadIdx.x;
    int start = H[b * NB];
    int end = (b == KBK - 1) ? ETOT : H[(b + 1) * NB];
    int cnt = end - start;
    bool useLds = (cnt <= MAXB);
    hist[t] = 0;
    __syncthreads();
    for (int i = t; i < cnt; i += 256) {
        int2 e = tmp[start + i];
        if (useLds) eb[i] = e;
        atomicAdd(&hist[(e.x >> 16) & 255], 1);
    }
    __syncthreads();
    sc[t] = hist[t]; __syncthreads();
    for (int d = 1; d < 256; d <<= 1) {
        int v = (t >= d) ? sc[t - d] : 0;
        __syncthreads();
        sc[t] += v;
        __syncthreads();
    }
    int pref = sc[t] - hist[t];
    int r = b / RBK, rh = b - r * RBK;
    int grow = rh * 256 + t;
    if (grow < N_NODES) rp[r * N_NODES + grow] = start + pref;
    cur[t] = start + pref;
    __syncthreads();
    for (int i = t; i < cnt; i += 256) {
        int2 e = useLds ? eb[i] : tmp[start + i];
        int rl = (e.x >> 16) & 255;
        int p = atomicAdd(&cur[rl], 1);
        cse[p] = make_int2(e.x & 0xFFFF, e.y);
    }
}

// ---------------- layer-1 spmm, all 3 views, merged table, x4 unroll -------
__global__ void spmm1_all_kernel(const ushort* __restrict__ xall,
                                 const int* __restrict__ rp, const int2* __restrict__ cse,
                                 float* __restrict__ Sp, float* __restrict__ Sf,
                                 float* __restrict__ Sn) {
    int wave = threadIdx.x >> 6, lane = threadIdx.x & 63;
    int row = blockIdx.x * 4 + wave;
    if (row >= N_NODES) return;
    bool lp = lane < 62, lf = lane < 37;
    int opx = lane;
    int ofn = 64 + 2 * lane;
    for (int r = 0; r < R_REL; r++) {
        int e0 = rp[r * N_NODES + row], e1 = rp[r * N_NODES + row + 1];
        float ap = 0.f, af = 0.f, an = 0.f;
        int e = e0;
        for (; e + 4 <= e1; e += 4) {
            int2 q0 = cse[e], q1 = cse[e + 1], q2 = cse[e + 2], q3 = cse[e + 3];
            const ushort* b0 = xall + (size_t)q0.x * 192;
            const ushort* b1 = xall + (size_t)q1.x * 192;
            const ushort* b2 = xall + (size_t)q2.x * 192;
            const ushort* b3 = xall + (size_t)q3.x * 192;
            ushort  p0 = b0[opx], p1 = b1[opx], p2 = b2[opx], p3 = b3[opx];
            ushort2 u0 = *(const ushort2*)&b0[ofn];
            ushort2 u1 = *(const ushort2*)&b1[ofn];
            ushort2 u2 = *(const ushort2*)&b2[ofn];
            ushort2 u3 = *(const ushort2*)&b3[ofn];
            float v0 = __int_as_float(q0.y), v1 = __int_as_float(q1.y);
            float v2 = __int_as_float(q2.y), v3 = __int_as_float(q3.y);
            ap += v0 * bf2f(p0) + v1 * bf2f(p1) + v2 * bf2f(p2) + v3 * bf2f(p3);
            af += v0 * bf2f(u0.x) + v1 * bf2f(u1.x) + v2 * bf2f(u2.x) + v3 * bf2f(u3.x);
            an += v0 * bf2f(u0.y) + v1 * bf2f(u1.y) + v2 * bf2f(u2.y) + v3 * bf2f(u3.y);
        }
        for (; e < e1; e++) {
            int2 q = cse[e];
            const ushort* b = xall + (size_t)q.x * 192;
            float v = __int_as_float(q.y);
            ap += v * bf2f(b[opx]);
            ushort2 u = *(const ushort2*)&b[ofn];
            af += v * bf2f(u.x);
            an += v * bf2f(u.y);
        }
        if (lp) Sp[row * 248 + r * 62 + lane] = ap;
        if (lf) { Sf[row * 148 + r * 37 + lane] = af; Sn[row * 148 + r * 37 + lane] = an; }
    }
}

// ---------------- GEMM1 ----------------
__launch_bounds__(256)
__global__ void gemm1_kernel(const float* __restrict__ x, const float* __restrict__ S,
                             const float* __restrict__ Ws, const float* __restrict__ bs,
                             const float* __restrict__ Wr, const float* __restrict__ br,
                             float* __restrict__ h, int din) {
    __shared__ float sA[64 * 63];
    __shared__ float sW[62 * 132];
    int t = threadIdx.x;
    int i0 = blockIdx.x * 64;
    int rg = t >> 5, cg = t & 31;
    float acc[8][4] = {};
    for (int s = 0; s < 5; s++) {
        const float* Aptr; int astride;
        if (s == 0) { Aptr = x; astride = din; }
        else        { Aptr = S + (s - 1) * din; astride = 4 * din; }
        const float* Wp = (s == 0) ? Ws : (Wr + (s - 1) * H_DIM * din);
        __syncthreads();
        for (int idx = t; idx < 64 * din; idx += 256) {
            int rr = idx / din, k = idx - rr * din;
            int grow = i0 + rr;
            sA[rr * 63 + k] = (grow < N_NODES) ? Aptr[grow * astride + k] : 0.f;
        }
        for (int idx = t; idx < H_DIM * din; idx += 256) {
            int j = idx / din, k = idx - j * din;
            sW[k * 132 + j] = Wp[j * din + k];
        }
        __syncthreads();
        for (int k = 0; k < din; k++) {
            float a[8];
            #pragma unroll
            for (int rr = 0; rr < 8; rr++) a[rr] = sA[(rg * 8 + rr) * 63 + k];
            float4 w = *(const float4*)&sW[k * 132 + cg * 4];
            #pragma unroll
            for (int rr = 0; rr < 8; rr++) {
                acc[rr][0] += a[rr] * w.x; acc[rr][1] += a[rr] * w.y;
                acc[rr][2] += a[rr] * w.z; acc[rr][3] += a[rr] * w.w;
            }
        }
    }
    int j0 = cg * 4;
    float btot[4];
    #pragma unroll
    for (int cc = 0; cc < 4; cc++) {
        float b = bs[j0 + cc];
        #pragma unroll
        for (int r = 0; r < R_REL; r++) b += br[r * H_DIM + j0 + cc];
        btot[cc] = b;
    }
    #pragma unroll
    for (int rr = 0; rr < 8; rr++) {
        int grow = i0 + rg * 8 + rr;
        if (grow < N_NODES) {
            float4 o;
            o.x = fmaxf((acc[rr][0] + btot[0]) * 0.2f, 0.f);
            o.y = fmaxf((acc[rr][1] + btot[1]) * 0.2f, 0.f);
            o.z = fmaxf((acc[rr][2] + btot[2]) * 0.2f, 0.f);
            o.w = fmaxf((acc[rr][3] + btot[3]) * 0.2f, 0.f);
            *(float4*)&h[grow * H_DIM + j0] = o;
        }
    }
}

// ---------------- GEMM2: Yself fp32 (ct=0), Yrel bf16 (ct=1..4) ------------
__launch_bounds__(256)
__global__ void gemm2_kernel(const float* __restrict__ h, const float* __restrict__ Ws2,
                             const float* __restrict__ Wr2, float* __restrict__ Yself,
                             ushort* __restrict__ Yrel) {
    __shared__ float sA[128 * 65];
    __shared__ float sW[64 * 68];
    int t = threadIdx.x;
    int i0 = blockIdx.x * 128;
    int ct = blockIdx.y;
    int rg = t >> 4, cg = t & 15;
    const float* Wp = (ct == 0) ? Ws2 : (Wr2 + (ct - 1) * 64 * H_DIM);
    float acc[8][4] = {};
    for (int kc = 0; kc < 2; kc++) {
        __syncthreads();
        for (int idx = t; idx < 128 * 64; idx += 256) {
            int rr = idx >> 6, k = idx & 63;
            int grow = i0 + rr;
            sA[rr * 65 + k] = (grow < N_NODES) ? h[grow * H_DIM + kc * 64 + k] : 0.f;
        }
        for (int idx = t; idx < 64 * 64; idx += 256) {
            int j = idx >> 6, k = idx & 63;
            sW[k * 68 + j] = Wp[j * H_DIM + kc * 64 + k];
        }
        __syncthreads();
        for (int k = 0; k < 64; k++) {
            float a[8];
            #pragma unroll
            for (int rr = 0; rr < 8; rr++) a[rr] = sA[(rg * 8 + rr) * 65 + k];
            float4 w = *(const float4*)&sW[k * 68 + cg * 4];
            #pragma unroll
            for (int rr = 0; rr < 8; rr++) {
                acc[rr][0] += a[rr] * w.x; acc[rr][1] += a[rr] * w.y;
                acc[rr][2] += a[rr] * w.z; acc[rr][3] += a[rr] * w.w;
            }
        }
    }
    #pragma unroll
    for (int rr = 0; rr < 8; rr++) {
        int grow = i0 + rg * 8 + rr;
        if (grow < N_NODES) {
            if (ct == 0) {
                float4 o = make_float4(acc[rr][0], acc[rr][1], acc[rr][2], acc[rr][3]);
                *(float4*)&Yself[(size_t)grow * 64 + cg * 4] = o;
            } else {
                ushort4 o;
                o.x = f2bf(acc[rr][0]); o.y = f2bf(acc[rr][1]);
                o.z = f2bf(acc[rr][2]); o.w = f2bf(acc[rr][3]);
                *(ushort4*)&Yrel[(size_t)grow * 256 + (ct - 1) * 64 + cg * 4] = o;
            }
        }
    }
}

// ------- spmm2 (all 3 views) + bias + /5 + gated fusion, x4 unroll ---------
__global__ void spmm2z_all_kernel(const float* __restrict__ Ysp, const ushort* __restrict__ Yrp,
                                  const float* __restrict__ Ysf, const ushort* __restrict__ Yrf,
                                  const float* __restrict__ Ysn, const ushort* __restrict__ Yrn,
                                  const int* __restrict__ rp, const int2* __restrict__ cse,
                                  const float* __restrict__ p_bs, const float* __restrict__ p_br,
                                  const float* __restrict__ f_bs, const float* __restrict__ f_br,
                                  const float* __restrict__ n_bs, const float* __restrict__ n_br,
                                  const float* __restrict__ gW, const float* __restrict__ gb,
                                  float* __restrict__ z) {
    int wave = threadIdx.x >> 6, lane = threadIdx.x & 63;
    int row = blockIdx.x * 4 + wave;
    if (row >= N_NODES) return;
    float aP = Ysp[(size_t)row * 64 + lane] + p_bs[lane]
             + p_br[lane] + p_br[64 + lane] + p_br[128 + lane] + p_br[192 + lane];
    float aF = Ysf[(size_t)row * 64 + lane] + f_bs[lane]
             + f_br[lane] + f_br[64 + lane] + f_br[128 + lane] + f_br[192 + lane];
    float aN = Ysn[(size_t)row * 64 + lane] + n_bs[lane]
             + n_br[lane] + n_br[64 + lane] + n_br[128 + lane] + n_br[192 + lane];
    for (int r = 0; r < R_REL; r++) {
        int e0 = rp[r * N_NODES + row], e1 = rp[r * N_NODES + row + 1];
        const ushort* yp = Yrp + r * 64 + lane;
        const ushort* yf = Yrf + r * 64 + lane;
        const ushort* yn = Yrn + r * 64 + lane;
        int e = e0;
        for (; e + 4 <= e1; e += 4) {
            int2 q0 = cse[e], q1 = cse[e + 1], q2 = cse[e + 2], q3 = cse[e + 3];
            size_t o0 = (size_t)q0.x * 256, o1 = (size_t)q1.x * 256;
            size_t o2 = (size_t)q2.x * 256, o3 = (size_t)q3.x * 256;
            float pp0 = bf2f(yp[o0]), pp1 = bf2f(yp[o1]), pp2 = bf2f(yp[o2]), pp3 = bf2f(yp[o3]);
            float ff0 = bf2f(yf[o0]), ff1 = bf2f(yf[o1]), ff2 = bf2f(yf[o2]), ff3 = bf2f(yf[o3]);
            float nn0 = bf2f(yn[o0]), nn1 = bf2f(yn[o1]), nn2 = bf2f(yn[o2]), nn3 = bf2f(yn[o3]);
            float v0 = __int_as_float(q0.y), v1 = __int_as_float(q1.y);
            float v2 = __int_as_float(q2.y), v3 = __int_as_float(q3.y);
            aP += v0 * pp0 + v1 * pp1 + v2 * pp2 + v3 * pp3;
            aF += v0 * ff0 + v1 * ff1 + v2 * ff2 + v3 * ff3;
            aN += v0 * nn0 + v1 * nn1 + v2 * nn2 + v3 * nn3;
        }
        for (; e < e1; e++) {
            int2 q = cse[e];
            size_t o = (size_t)q.x * 256;
            float v = __int_as_float(q.y);
            aP += v * bf2f(yp[o]);
            aF += v * bf2f(yf[o]);
            aN += v * bf2f(yn[o]);
        }
    }
    aP *= 0.2f; aF *= 0.2f; aN *= 0.2f;
    float sp = aP * gW[lane], sf = aF * gW[64 + lane], sn = aN * gW[128 + lane];
    #pragma unroll
    for (int d = 32; d >= 1; d >>= 1) {
        sp += __shfl_xor(sp, d);
        sf += __shfl_xor(sf, d);
        sn += __shfl_xor(sn, d);
    }
    sp += gb[0]; sf += gb[1]; sn += gb[2];
    float m = fmaxf(sp, fmaxf(sf, sn));
    float ep = __expf(sp - m), ef = __expf(sf - m), en = __expf(sn - m);
    float inv = 1.f / (ep + ef + en);
    z[row * 64 + lane] = (ep * aP + ef * aF + en * aN) * inv;
}

// -------- decoder prep: za = z@Wa^T + b1, zb = z@Wb^T (per node) -----------
// wave per node; lane j owns w1[j][0:64] and w1[j][64:128] in registers
__launch_bounds__(256)
__global__ void dec_prep_kernel(const float* __restrict__ z, const float* __restrict__ w1,
                                const float* __restrict__ b1, float* __restrict__ za,
                                float* __restrict__ zb, int nwaves) {
    int lane = threadIdx.x & 63;
    int wid = (blockIdx.x * blockDim.x + threadIdx.x) >> 6;
    float wa[64], wb[64];
    const float* wr = w1 + lane * 256;
    #pragma unroll
    for (int k = 0; k < 64; k += 4) {
        float4 c = *(const float4*)&wr[k];
        wa[k] = c.x; wa[k + 1] = c.y; wa[k + 2] = c.z; wa[k + 3] = c.w;
        float4 d = *(const float4*)&wr[64 + k];
        wb[k] = d.x; wb[k + 1] = d.y; wb[k + 2] = d.z; wb[k + 3] = d.w;
    }
    float b1v = b1[lane];
    for (int n = wid; n < N_NODES; n += nwaves) {
        const float4* zp = (const float4*)(z + (size_t)n * 64);
        float ha = b1v, hb = 0.f;
        #pragma unroll
        for (int kc = 0; kc < 16; kc++) {
            float4 v = zp[kc];               // wave-uniform broadcast load
            int k = kc * 4;
            ha += v.x * wa[k] + v.y * wa[k + 1] + v.z * wa[k + 2] + v.w * wa[k + 3];
            hb += v.x * wb[k] + v.y * wb[k + 1] + v.z * wb[k + 2] + v.w * wb[k + 3];
        }
        za[(size_t)n * 64 + lane] = ha;
        zb[(size_t)n * 64 + lane] = hb;
    }
}

// -------- decoder: wave per edge, Wc/Wd in registers, hid scalar per lane --
__launch_bounds__(256)
__global__ void decoder2_kernel(const float* __restrict__ z, const float* __restrict__ za,
                                const float* __restrict__ zb, const int* __restrict__ esrc,
                                const int* __restrict__ edst, const float* __restrict__ w1,
                                const float* __restrict__ w2, const float* __restrict__ b2,
                                float* __restrict__ out, int nwaves) {
    int lane = threadIdx.x & 63;
    int wid = (blockIdx.x * blockDim.x + threadIdx.x) >> 6;
    float wc[64], wd[64];
    const float* wr = w1 + lane * 256;
    #pragma unroll
    for (int k = 0; k < 64; k += 4) {
        float4 c = *(const float4*)&wr[128 + k];
        wc[k] = c.x; wc[k + 1] = c.y; wc[k + 2] = c.z; wc[k + 3] = c.w;
        float4 d = *(const float4*)&wr[192 + k];
        wd[k] = d.x; wd[k + 1] = d.y; wd[k + 2] = d.z; wd[k + 3] = d.w;
    }
    float w2j = w2[lane];
    float b2v = b2[0];
    for (int e = wid; e < ED_EDGES; e += nwaves) {
        int s = esrc[e];
        int d = edst[e];
        const float4* zsp = (const float4*)(z + (size_t)s * 64);
        const float4* zdp = (const float4*)(z + (size_t)d * 64);
        float hid = za[(size_t)s * 64 + lane] + zb[(size_t)d * 64 + lane];
        #pragma unroll
        for (int kc = 0; kc < 16; kc++) {
            float4 a = zsp[kc];              // wave-uniform broadcast loads
            float4 b = zdp[kc];
            int k = kc * 4;
            float p0 = a.x * b.x, q0 = fabsf(a.x - b.x);
            float p1 = a.y * b.y, q1 = fabsf(a.y - b.y);
            float p2 = a.z * b.z, q2 = fabsf(a.z - b.z);
            float p3 = a.w * b.w, q3 = fabsf(a.w - b.w);
            hid += p0 * wc[k] + q0 * wd[k]
                 + p1 * wc[k + 1] + q1 * wd[k + 1]
                 + p2 * wc[k + 2] + q2 * wd[k + 2]
                 + p3 * wc[k + 3] + q3 * wd[k + 3];
        }
        float v = fmaxf(hid, 0.f) * w2j;
        #pragma unroll
        for (int m = 32; m >= 1; m >>= 1) v += __shfl_xor(v, m);
        if (lane == 0) out[e] = v + b2v;
    }
}

// ---------------- host ----------------
extern "C" void kernel_launch(void* const* d_in, const int* in_sizes, int n_in,
                              void* d_out, int out_size, void* d_ws, size_t ws_size,
                              hipStream_t stream) {
    const float* x_p = (const float*)d_in[0];
    const float* x_f = (const float*)d_in[1];
    const float* x_n = (const float*)d_in[2];
    const float* p1_Ws = (const float*)d_in[3];  const float* p1_bs = (const float*)d_in[4];
    const float* p1_Wr = (const float*)d_in[5];  const float* p1_br = (const float*)d_in[6];
    const float* p2_Ws = (const float*)d_in[7];  const float* p2_bs = (const float*)d_in[8];
    const float* p2_Wr = (const float*)d_in[9];  const float* p2_br = (const float*)d_in[10];
    const float* f1_Ws = (const float*)d_in[11]; const float* f1_bs = (const float*)d_in[12];
    const float* f1_Wr = (const float*)d_in[13]; const float* f1_br = (const float*)d_in[14];
    const float* f2_Ws = (const float*)d_in[15]; const float* f2_bs = (const float*)d_in[16];
    const float* f2_Wr = (const float*)d_in[17]; const float* f2_br = (const float*)d_in[18];
    const float* n1_Ws = (const float*)d_in[19]; const float* n1_bs = (const float*)d_in[20];
    const float* n1_Wr = (const float*)d_in[21]; const float* n1_br = (const float*)d_in[22];
    const float* n2_Ws = (const float*)d_in[23]; const float* n2_bs = (const float*)d_in[24];
    const float* n2_Wr = (const float*)d_in[25]; const float* n2_br = (const float*)d_in[26];
    const float* gate_W = (const float*)d_in[27]; const float* gate_b = (const float*)d_in[28];
    const float* dec_W1 = (const float*)d_in[29]; const float* dec_b1 = (const float*)d_in[30];
    const float* dec_W2 = (const float*)d_in[31]; const float* dec_b2 = (const float*)d_in[32];
    const int*   adj_rows = (const int*)d_in[33];
    const int*   adj_cols = (const int*)d_in[34];
    const float* adj_vals = (const float*)d_in[35];
    const int*   edge_src = (const int*)d_in[36];
    const int*   edge_dst = (const int*)d_in[37];

    char* ws = (char*)d_ws;
    int*    rp   = (int*)(ws + WS_RP);
    int*    H    = (int*)(ws + WS_HIST);
    int*    bsum = (int*)(ws + WS_BSUM);
    int2*   cse  = (int2*)(ws + WS_CV);
    int2*   tmp  = (int2*)(ws + WS_TMP);
    ushort* xall = (ushort*)(ws + WS_XALL);
    float*  S_p = (float*)(ws + WS_SP);
    float*  S_f = (float*)(ws + WS_SF);
    float*  S_n = (float*)(ws + WS_SN);
    float*  h_p = (float*)(ws + WS_HPR);
    float*  h_f = (float*)(ws + WS_HF);
    float*  h_n = (float*)(ws + WS_HN);
    float*  Ys_p = (float*)(ws + WS_YSP);  ushort* Yr_p = (ushort*)(ws + WS_YRP);
    float*  Ys_f = (float*)(ws + WS_YSF);  ushort* Yr_f = (ushort*)(ws + WS_YRF);
    float*  Ys_n = (float*)(ws + WS_YSN);  ushort* Yr_n = (ushort*)(ws + WS_YRN);
    float*  z   = (float*)(ws + WS_Z);
    float*  za  = (float*)(ws + WS_ZA);
    float*  zb  = (float*)(ws + WS_ZB);
    float*  out = (float*)d_out;

    // bf16 staging of node features (merged, 384B-stride, zero-padded)
    cast_xall_kernel<<<(N_NODES * 192 + 255) / 256, 256, 0, stream>>>(x_p, x_f, x_n, xall);

    // radix CSR build: hist -> scan -> block-private scatter -> per-bucket sort
    radix_hist_kernel<<<NB, 256, 0, stream>>>(adj_rows, H);
    scan_part_kernel<<<SCB, 256, 0, stream>>>(H, bsum);
    scan_bsum_kernel<<<1, 512, 0, stream>>>(bsum, rp);
    scan_final_kernel<<<SCB, 256, 0, stream>>>(H, bsum);
    radix_scatter_kernel<<<NB, 256, 0, stream>>>(adj_rows, adj_cols, adj_vals, H, tmp);
    bucket_sort_kernel<<<KBK, 256, 0, stream>>>(tmp, H, rp, cse);

    // layer-1 spmm for all 3 views
    spmm1_all_kernel<<<N_NODES / 4, 256, 0, stream>>>(xall, rp, cse, S_p, S_f, S_n);

    // layer-1 GEMMs -> h_v (fp32)
    int g1 = (N_NODES + 63) / 64;
    gemm1_kernel<<<g1, 256, 0, stream>>>(x_p, S_p, p1_Ws, p1_bs, p1_Wr, p1_br, h_p, 62);
    gemm1_kernel<<<g1, 256, 0, stream>>>(x_f, S_f, f1_Ws, f1_bs, f1_Wr, f1_br, h_f, 37);
    gemm1_kernel<<<g1, 256, 0, stream>>>(x_n, S_n, n1_Ws, n1_bs, n1_Wr, n1_br, h_n, 37);

    // layer-2 GEMMs (matmul-first): Yself fp32 + Yrel bf16 per view
    dim3 g2((N_NODES + 127) / 128, 5);
    gemm2_kernel<<<g2, 256, 0, stream>>>(h_p, p2_Ws, p2_Wr, Ys_p, Yr_p);
    gemm2_kernel<<<g2, 256, 0, stream>>>(h_f, f2_Ws, f2_Wr, Ys_f, Yr_f);
    gemm2_kernel<<<g2, 256, 0, stream>>>(h_n, n2_Ws, n2_Wr, Ys_n, Yr_n);

    // spmm2 (all views) + bias + gated fusion -> z
    spmm2z_all_kernel<<<N_NODES / 4, 256, 0, stream>>>(
        Ys_p, Yr_p, Ys_f, Yr_f, Ys_n, Yr_n, rp, cse,
        p2_bs, p2_br, f2_bs, f2_br, n2_bs, n2_br, gate_W, gate_b, z);

    // edge decoder: per-node prep (za/zb) then wave-per-edge
    dec_prep_kernel<<<256, 256, 0, stream>>>(z, dec_W1, dec_b1, za, zb, 256 * 4);
    decoder2_kernel<<<1024, 256, 0, stream>>>(
        z, za, zb, edge_src, edge_dst, dec_W1, dec_W2, dec_b2, out, 1024 * 4);
}

// Round 7
// 1558.156 us; speedup vs baseline: 1.0509x; 1.0509x over previous
//
#include <hip/hip_runtime.h>

#define N_NODES 50000
#define R_REL   4
#define E_NNZ   800000
#define ED_EDGES 200000
#define H_DIM   128
#define L_DIM   64

#define RN_TOTAL (R_REL * N_NODES)    // 200000
#define ETOT     (R_REL * E_NNZ)      // 3,200,000

// ----- radix CSR-build constants -----
#define EPB   8192                    // edges per radix block
#define NB    391                     // ceil(ETOT/EPB)
#define RBK   196                     // row buckets per relation (256 rows each)
#define KBK   (R_REL * RBK)           // 784 total buckets
#define HTOT  (KBK * NB)              // 306,544 histogram entries
#define SCB   300                     // ceil(HTOT/1024) scan blocks
#define MAXB  6144                    // LDS edge capacity per bucket

// ---------------- workspace layout (bytes); budget <= 213,601,536 ----------
#define WS_RP    0u            // (RN+1) int -> 800,256
#define WS_HIST  800256u       // HTOT int -> 2,026,496 (pad)
#define WS_BSUM  2026496u      // 1024 int -> 2,030,592
#define WS_CV    2030592u      // ETOT int2 = 25.6e6 -> 27,630,592   (final cse, persistent)
#define WS_TMP   27630720u     // ETOT int2 = 25.6e6 -> 53,230,720   (bucketed tmp; later h_n)
#define WS_XALL  53230720u     // N*192 ushort = 19.2e6 -> 72,430,720 (later Ys_p)
#define WS_SP    72430720u     // N*248 f32 = 49.6e6 -> 122,030,720  (later h_f, Ys_f)
#define WS_SF    122030720u    // N*148 f32 = 29.6e6 -> 151,630,720  (later Yr_p)
#define WS_SN    151630720u    // N*148 f32 = 29.6e6 -> 181,230,720  (later Yr_f)
#define WS_HPR   181230720u    // N*128 f32 = 25.6e6 -> 206,830,720  (h_p; later Ys_n, z)
#define WS_HN    WS_TMP                    // h_n reuses tmp (dead after bucket_sort)
#define WS_HF    WS_SP                     // h_f reuses S_p (dead after gemm1_p)
#define WS_YSP   WS_XALL                   // 12.8e6 (xall dead after spmm1)
#define WS_YSF   (WS_SP + 25600000u)       // 98,030,720 (S_p tail)
#define WS_YRP   WS_SF                     // 25.6e6 (S_f dead after gemm1_f)
#define WS_YRF   WS_SN                     // 25.6e6 (S_n dead after gemm1_n)
#define WS_YSN   WS_HPR                    // 12.8e6 (h_p dead after gemm2_p)
#define WS_YRN   WS_HF                     // 25.6e6 (h_f dead after gemm2_f)
#define WS_Z     194030720u                // 12.8e6 -> 206,830,720 (h_p tail)

__device__ __forceinline__ ushort f2bf(float f) {
    unsigned u = __float_as_uint(f);
    unsigned r = (u + 0x7fffu + ((u >> 16) & 1u)) >> 16;   // RNE
    return (ushort)r;
}
__device__ __forceinline__ float bf2f(ushort u) {
    return __uint_as_float(((unsigned)u) << 16);
}

// ---------------- bf16 staging: one merged 384B-stride table ----------------
__global__ void cast_xall_kernel(const float* __restrict__ xp, const float* __restrict__ xf,
                                 const float* __restrict__ xn, ushort* __restrict__ xall) {
    int i = blockIdx.x * 256 + threadIdx.x;
    if (i >= N_NODES * 192) return;
    int node = i / 192, k = i - node * 192;
    float v = 0.f;
    if (k < 62) v = xp[node * 62 + k];
    else if (k >= 64 && k < 138) {
        int j = k - 64, d = j >> 1;
        v = (j & 1) ? xn[node * 37 + d] : xf[node * 37 + d];
    }
    xall[i] = f2bf(v);
}

// ---------------- radix CSR build ----------------
__global__ void radix_hist_kernel(const int* __restrict__ rows, int* __restrict__ H) {
    __shared__ int hist[KBK];
    int blk = blockIdx.x, t = threadIdx.x;
    for (int i = t; i < KBK; i += 256) hist[i] = 0;
    __syncthreads();
    int base = blk * EPB;
    #pragma unroll 1
    for (int i = 0; i < EPB / 256; i++) {
        int g = base + i * 256 + t;
        if (g < ETOT) {
            int r = g / E_NNZ;
            atomicAdd(&hist[r * RBK + (rows[g] >> 8)], 1);
        }
    }
    __syncthreads();
    for (int i = t; i < KBK; i += 256) H[i * NB + blk] = hist[i];
}

__global__ void scan_part_kernel(const int* __restrict__ H, int* __restrict__ bsum) {
    __shared__ int red[256];
    int base = blockIdx.x * 1024, t = threadIdx.x;
    int s = 0;
    #pragma unroll
    for (int i = 0; i < 4; i++) {
        int idx = base + i * 256 + t;
        if (idx < HTOT) s += H[idx];
    }
    red[t] = s; __syncthreads();
    for (int d = 128; d > 0; d >>= 1) {
        if (t < d) red[t] += red[t + d];
        __syncthreads();
    }
    if (t == 0) bsum[blockIdx.x] = red[0];
}

__global__ void scan_bsum_kernel(int* __restrict__ bsum, int* __restrict__ rp) {
    __shared__ int sh[512];
    int t = threadIdx.x;
    int v = (t < SCB) ? bsum[t] : 0;
    sh[t] = v; __syncthreads();
    for (int d = 1; d < 512; d <<= 1) {
        int u = (t >= d) ? sh[t - d] : 0;
        __syncthreads();
        sh[t] += u;
        __syncthreads();
    }
    if (t < SCB) bsum[t] = sh[t] - v;
    if (t == 0) rp[RN_TOTAL] = ETOT;
}

__global__ void scan_final_kernel(int* __restrict__ H, const int* __restrict__ bsum) {
    __shared__ int sh[256];
    int base = blockIdx.x * 1024, t = threadIdx.x;
    int c[4]; int s = 0;
    #pragma unroll
    for (int i = 0; i < 4; i++) {
        int idx = base + t * 4 + i;
        c[i] = (idx < HTOT) ? H[idx] : 0;
        s += c[i];
    }
    sh[t] = s; __syncthreads();
    for (int d = 1; d < 256; d <<= 1) {
        int u = (t >= d) ? sh[t - d] : 0;
        __syncthreads();
        sh[t] += u;
        __syncthreads();
    }
    int off = bsum[blockIdx.x] + sh[t] - s;
    #pragma unroll
    for (int i = 0; i < 4; i++) {
        int idx = base + t * 4 + i;
        if (idx < HTOT) H[idx] = off;
        off += c[i];
    }
}

__global__ void radix_scatter_kernel(const int* __restrict__ rows, const int* __restrict__ cols,
                                     const float* __restrict__ vals, const int* __restrict__ H,
                                     int2* __restrict__ tmp) {
    __shared__ int cur[KBK];
    int blk = blockIdx.x, t = threadIdx.x;
    for (int i = t; i < KBK; i += 256) cur[i] = H[i * NB + blk];
    __syncthreads();
    int base = blk * EPB;
    #pragma unroll 1
    for (int i = 0; i < EPB / 256; i++) {
        int g = base + i * 256 + t;
        if (g < ETOT) {
            int r = g / E_NNZ;
            int row = rows[g];
            int b = r * RBK + (row >> 8);
            int p = atomicAdd(&cur[b], 1);
            tmp[p] = make_int2(cols[g] | ((row & 255) << 16), __float_as_int(vals[g]));
        }
    }
}

__launch_bounds__(256)
__global__ void bucket_sort_kernel(const int2* __restrict__ tmp, const int* __restrict__ H,
                                   int* __restrict__ rp, int2* __restrict__ cse) {
    __shared__ int hist[256];
    __shared__ int sc[256];
    __shared__ int cur[256];
    __shared__ int2 eb[MAXB];
    int b = blockIdx.x, t = threadIdx.x;
    int start = H[b * NB];
    int end = (b == KBK - 1) ? ETOT : H[(b + 1) * NB];
    int cnt = end - start;
    bool useLds = (cnt <= MAXB);
    hist[t] = 0;
    __syncthreads();
    for (int i = t; i < cnt; i += 256) {
        int2 e = tmp[start + i];
        if (useLds) eb[i] = e;
        atomicAdd(&hist[(e.x >> 16) & 255], 1);
    }
    __syncthreads();
    sc[t] = hist[t]; __syncthreads();
    for (int d = 1; d < 256; d <<= 1) {
        int v = (t >= d) ? sc[t - d] : 0;
        __syncthreads();
        sc[t] += v;
        __syncthreads();
    }
    int pref = sc[t] - hist[t];
    int r = b / RBK, rh = b - r * RBK;
    int grow = rh * 256 + t;
    if (grow < N_NODES) rp[r * N_NODES + grow] = start + pref;
    cur[t] = start + pref;
    __syncthreads();
    for (int i = t; i < cnt; i += 256) {
        int2 e = useLds ? eb[i] : tmp[start + i];
        int rl = (e.x >> 16) & 255;
        int p = atomicAdd(&cur[rl], 1);
        cse[p] = make_int2(e.x & 0xFFFF, e.y);
    }
}

// ---------------- layer-1 spmm, all 3 views, merged table, x4 unroll -------
__global__ void spmm1_all_kernel(const ushort* __restrict__ xall,
                                 const int* __restrict__ rp, const int2* __restrict__ cse,
                                 float* __restrict__ Sp, float* __restrict__ Sf,
                                 float* __restrict__ Sn) {
    int wave = threadIdx.x >> 6, lane = threadIdx.x & 63;
    int row = blockIdx.x * 4 + wave;
    if (row >= N_NODES) return;
    bool lp = lane < 62, lf = lane < 37;
    int opx = lane;
    int ofn = 64 + 2 * lane;
    for (int r = 0; r < R_REL; r++) {
        int e0 = rp[r * N_NODES + row], e1 = rp[r * N_NODES + row + 1];
        float ap = 0.f, af = 0.f, an = 0.f;
        int e = e0;
        for (; e + 4 <= e1; e += 4) {
            int2 q0 = cse[e], q1 = cse[e + 1], q2 = cse[e + 2], q3 = cse[e + 3];
            const ushort* b0 = xall + (size_t)q0.x * 192;
            const ushort* b1 = xall + (size_t)q1.x * 192;
            const ushort* b2 = xall + (size_t)q2.x * 192;
            const ushort* b3 = xall + (size_t)q3.x * 192;
            ushort  p0 = b0[opx], p1 = b1[opx], p2 = b2[opx], p3 = b3[opx];
            ushort2 u0 = *(const ushort2*)&b0[ofn];
            ushort2 u1 = *(const ushort2*)&b1[ofn];
            ushort2 u2 = *(const ushort2*)&b2[ofn];
            ushort2 u3 = *(const ushort2*)&b3[ofn];
            float v0 = __int_as_float(q0.y), v1 = __int_as_float(q1.y);
            float v2 = __int_as_float(q2.y), v3 = __int_as_float(q3.y);
            ap += v0 * bf2f(p0) + v1 * bf2f(p1) + v2 * bf2f(p2) + v3 * bf2f(p3);
            af += v0 * bf2f(u0.x) + v1 * bf2f(u1.x) + v2 * bf2f(u2.x) + v3 * bf2f(u3.x);
            an += v0 * bf2f(u0.y) + v1 * bf2f(u1.y) + v2 * bf2f(u2.y) + v3 * bf2f(u3.y);
        }
        for (; e < e1; e++) {
            int2 q = cse[e];
            const ushort* b = xall + (size_t)q.x * 192;
            float v = __int_as_float(q.y);
            ap += v * bf2f(b[opx]);
            ushort2 u = *(const ushort2*)&b[ofn];
            af += v * bf2f(u.x);
            an += v * bf2f(u.y);
        }
        if (lp) Sp[row * 248 + r * 62 + lane] = ap;
        if (lf) { Sf[row * 148 + r * 37 + lane] = af; Sn[row * 148 + r * 37 + lane] = an; }
    }
}

// ---------------- GEMM1 ----------------
__launch_bounds__(256)
__global__ void gemm1_kernel(const float* __restrict__ x, const float* __restrict__ S,
                             const float* __restrict__ Ws, const float* __restrict__ bs,
                             const float* __restrict__ Wr, const float* __restrict__ br,
                             float* __restrict__ h, int din) {
    __shared__ float sA[64 * 63];
    __shared__ float sW[62 * 132];
    int t = threadIdx.x;
    int i0 = blockIdx.x * 64;
    int rg = t >> 5, cg = t & 31;
    float acc[8][4] = {};
    for (int s = 0; s < 5; s++) {
        const float* Aptr; int astride;
        if (s == 0) { Aptr = x; astride = din; }
        else        { Aptr = S + (s - 1) * din; astride = 4 * din; }
        const float* Wp = (s == 0) ? Ws : (Wr + (s - 1) * H_DIM * din);
        __syncthreads();
        for (int idx = t; idx < 64 * din; idx += 256) {
            int rr = idx / din, k = idx - rr * din;
            int grow = i0 + rr;
            sA[rr * 63 + k] = (grow < N_NODES) ? Aptr[grow * astride + k] : 0.f;
        }
        for (int idx = t; idx < H_DIM * din; idx += 256) {
            int j = idx / din, k = idx - j * din;
            sW[k * 132 + j] = Wp[j * din + k];
        }
        __syncthreads();
        for (int k = 0; k < din; k++) {
            float a[8];
            #pragma unroll
            for (int rr = 0; rr < 8; rr++) a[rr] = sA[(rg * 8 + rr) * 63 + k];
            float4 w = *(const float4*)&sW[k * 132 + cg * 4];
            #pragma unroll
            for (int rr = 0; rr < 8; rr++) {
                acc[rr][0] += a[rr] * w.x; acc[rr][1] += a[rr] * w.y;
                acc[rr][2] += a[rr] * w.z; acc[rr][3] += a[rr] * w.w;
            }
        }
    }
    int j0 = cg * 4;
    float btot[4];
    #pragma unroll
    for (int cc = 0; cc < 4; cc++) {
        float b = bs[j0 + cc];
        #pragma unroll
        for (int r = 0; r < R_REL; r++) b += br[r * H_DIM + j0 + cc];
        btot[cc] = b;
    }
    #pragma unroll
    for (int rr = 0; rr < 8; rr++) {
        int grow = i0 + rg * 8 + rr;
        if (grow < N_NODES) {
            float4 o;
            o.x = fmaxf((acc[rr][0] + btot[0]) * 0.2f, 0.f);
            o.y = fmaxf((acc[rr][1] + btot[1]) * 0.2f, 0.f);
            o.z = fmaxf((acc[rr][2] + btot[2]) * 0.2f, 0.f);
            o.w = fmaxf((acc[rr][3] + btot[3]) * 0.2f, 0.f);
            *(float4*)&h[grow * H_DIM + j0] = o;
        }
    }
}

// ---------------- GEMM2: Yself fp32 (ct=0), Yrel bf16 (ct=1..4) ------------
__launch_bounds__(256)
__global__ void gemm2_kernel(const float* __restrict__ h, const float* __restrict__ Ws2,
                             const float* __restrict__ Wr2, float* __restrict__ Yself,
                             ushort* __restrict__ Yrel) {
    __shared__ float sA[128 * 65];
    __shared__ float sW[64 * 68];
    int t = threadIdx.x;
    int i0 = blockIdx.x * 128;
    int ct = blockIdx.y;
    int rg = t >> 4, cg = t & 15;
    const float* Wp = (ct == 0) ? Ws2 : (Wr2 + (ct - 1) * 64 * H_DIM);
    float acc[8][4] = {};
    for (int kc = 0; kc < 2; kc++) {
        __syncthreads();
        for (int idx = t; idx < 128 * 64; idx += 256) {
            int rr = idx >> 6, k = idx & 63;
            int grow = i0 + rr;
            sA[rr * 65 + k] = (grow < N_NODES) ? h[grow * H_DIM + kc * 64 + k] : 0.f;
        }
        for (int idx = t; idx < 64 * 64; idx += 256) {
            int j = idx >> 6, k = idx & 63;
            sW[k * 68 + j] = Wp[j * H_DIM + kc * 64 + k];
        }
        __syncthreads();
        for (int k = 0; k < 64; k++) {
            float a[8];
            #pragma unroll
            for (int rr = 0; rr < 8; rr++) a[rr] = sA[(rg * 8 + rr) * 65 + k];
            float4 w = *(const float4*)&sW[k * 68 + cg * 4];
            #pragma unroll
            for (int rr = 0; rr < 8; rr++) {
                acc[rr][0] += a[rr] * w.x; acc[rr][1] += a[rr] * w.y;
                acc[rr][2] += a[rr] * w.z; acc[rr][3] += a[rr] * w.w;
            }
        }
    }
    #pragma unroll
    for (int rr = 0; rr < 8; rr++) {
        int grow = i0 + rg * 8 + rr;
        if (grow < N_NODES) {
            if (ct == 0) {
                float4 o = make_float4(acc[rr][0], acc[rr][1], acc[rr][2], acc[rr][3]);
                *(float4*)&Yself[(size_t)grow * 64 + cg * 4] = o;
            } else {
                ushort4 o;
                o.x = f2bf(acc[rr][0]); o.y = f2bf(acc[rr][1]);
                o.z = f2bf(acc[rr][2]); o.w = f2bf(acc[rr][3]);
                *(ushort4*)&Yrel[(size_t)grow * 256 + (ct - 1) * 64 + cg * 4] = o;
            }
        }
    }
}

// ------- spmm2 (all 3 views) + bias + /5 + gated fusion, x4 unroll ---------
__global__ void spmm2z_all_kernel(const float* __restrict__ Ysp, const ushort* __restrict__ Yrp,
                                  const float* __restrict__ Ysf, const ushort* __restrict__ Yrf,
                                  const float* __restrict__ Ysn, const ushort* __restrict__ Yrn,
                                  const int* __restrict__ rp, const int2* __restrict__ cse,
                                  const float* __restrict__ p_bs, const float* __restrict__ p_br,
                                  const float* __restrict__ f_bs, const float* __restrict__ f_br,
                                  const float* __restrict__ n_bs, const float* __restrict__ n_br,
                                  const float* __restrict__ gW, const float* __restrict__ gb,
                                  float* __restrict__ z) {
    int wave = threadIdx.x >> 6, lane = threadIdx.x & 63;
    int row = blockIdx.x * 4 + wave;
    if (row >= N_NODES) return;
    float aP = Ysp[(size_t)row * 64 + lane] + p_bs[lane]
             + p_br[lane] + p_br[64 + lane] + p_br[128 + lane] + p_br[192 + lane];
    float aF = Ysf[(size_t)row * 64 + lane] + f_bs[lane]
             + f_br[lane] + f_br[64 + lane] + f_br[128 + lane] + f_br[192 + lane];
    float aN = Ysn[(size_t)row * 64 + lane] + n_bs[lane]
             + n_br[lane] + n_br[64 + lane] + n_br[128 + lane] + n_br[192 + lane];
    for (int r = 0; r < R_REL; r++) {
        int e0 = rp[r * N_NODES + row], e1 = rp[r * N_NODES + row + 1];
        const ushort* yp = Yrp + r * 64 + lane;
        const ushort* yf = Yrf + r * 64 + lane;
        const ushort* yn = Yrn + r * 64 + lane;
        int e = e0;
        for (; e + 4 <= e1; e += 4) {
            int2 q0 = cse[e], q1 = cse[e + 1], q2 = cse[e + 2], q3 = cse[e + 3];
            size_t o0 = (size_t)q0.x * 256, o1 = (size_t)q1.x * 256;
            size_t o2 = (size_t)q2.x * 256, o3 = (size_t)q3.x * 256;
            float pp0 = bf2f(yp[o0]), pp1 = bf2f(yp[o1]), pp2 = bf2f(yp[o2]), pp3 = bf2f(yp[o3]);
            float ff0 = bf2f(yf[o0]), ff1 = bf2f(yf[o1]), ff2 = bf2f(yf[o2]), ff3 = bf2f(yf[o3]);
            float nn0 = bf2f(yn[o0]), nn1 = bf2f(yn[o1]), nn2 = bf2f(yn[o2]), nn3 = bf2f(yn[o3]);
            float v0 = __int_as_float(q0.y), v1 = __int_as_float(q1.y);
            float v2 = __int_as_float(q2.y), v3 = __int_as_float(q3.y);
            aP += v0 * pp0 + v1 * pp1 + v2 * pp2 + v3 * pp3;
            aF += v0 * ff0 + v1 * ff1 + v2 * ff2 + v3 * ff3;
            aN += v0 * nn0 + v1 * nn1 + v2 * nn2 + v3 * nn3;
        }
        for (; e < e1; e++) {
            int2 q = cse[e];
            size_t o = (size_t)q.x * 256;
            float v = __int_as_float(q.y);
            aP += v * bf2f(yp[o]);
            aF += v * bf2f(yf[o]);
            aN += v * bf2f(yn[o]);
        }
    }
    aP *= 0.2f; aF *= 0.2f; aN *= 0.2f;
    float sp = aP * gW[lane], sf = aF * gW[64 + lane], sn = aN * gW[128 + lane];
    #pragma unroll
    for (int d = 32; d >= 1; d >>= 1) {
        sp += __shfl_xor(sp, d);
        sf += __shfl_xor(sf, d);
        sn += __shfl_xor(sn, d);
    }
    sp += gb[0]; sf += gb[1]; sn += gb[2];
    float m = fmaxf(sp, fmaxf(sf, sn));
    float ep = __expf(sp - m), ef = __expf(sf - m), en = __expf(sn - m);
    float inv = 1.f / (ep + ef + en);
    z[row * 64 + lane] = (ep * aP + ef * aF + en * aN) * inv;
}

// -------- decoder: thread per edge, full W1 in LDS (broadcast ds_read) -----
// hid[64] in VGPRs; per-edge gathers only zs+zd (512 B). b1/w2/b2 via uniform
// scalar loads (LDS is at the 64 KB/WG cap).
__launch_bounds__(256)
__global__ void decoder3_kernel(const float* __restrict__ z, const int* __restrict__ esrc,
                                const int* __restrict__ edst, const float* __restrict__ w1,
                                const float* __restrict__ b1, const float* __restrict__ w2,
                                const float* __restrict__ b2, float* __restrict__ out) {
    __shared__ float sW1[16384];          // 64 KB: rows j of [wa|wb|wc|wd]
    int t = threadIdx.x;
    for (int i = t; i < 4096; i += 256)
        ((float4*)sW1)[i] = ((const float4*)w1)[i];
    __syncthreads();
    int e = blockIdx.x * 256 + t;
    if (e >= ED_EDGES) return;
    const float4* zs = (const float4*)(z + (size_t)esrc[e] * 64);
    const float4* zd = (const float4*)(z + (size_t)edst[e] * 64);
    float hid[64];
    #pragma unroll
    for (int j = 0; j < 64; j++) hid[j] = 0.f;
    #pragma unroll 1
    for (int kc = 0; kc < 16; kc++) {
        float4 a = zs[kc];
        float4 b = zd[kc];
        float4 p, q;
        p.x = a.x * b.x; q.x = fabsf(a.x - b.x);
        p.y = a.y * b.y; q.y = fabsf(a.y - b.y);
        p.z = a.z * b.z; q.z = fabsf(a.z - b.z);
        p.w = a.w * b.w; q.w = fabsf(a.w - b.w);
        const float* wb0 = sW1 + kc * 4;
        #pragma unroll
        for (int j = 0; j < 64; j++) {
            const float* wr = wb0 + j * 256;
            float4 wa = *(const float4*)(wr);          // broadcast ds_read_b128
            float4 wbv = *(const float4*)(wr + 64);
            float4 wc = *(const float4*)(wr + 128);
            float4 wd = *(const float4*)(wr + 192);
            hid[j] += a.x * wa.x + a.y * wa.y + a.z * wa.z + a.w * wa.w
                    + b.x * wbv.x + b.y * wbv.y + b.z * wbv.z + b.w * wbv.w
                    + p.x * wc.x + p.y * wc.y + p.z * wc.z + p.w * wc.w
                    + q.x * wd.x + q.y * wd.y + q.z * wd.z + q.w * wd.w;
        }
    }
    float logit = b2[0];
    #pragma unroll
    for (int j = 0; j < 64; j++)
        logit += fmaxf(hid[j] + b1[j], 0.f) * w2[j];   // uniform s_loads
    out[e] = logit;
}

// ---------------- host ----------------
extern "C" void kernel_launch(void* const* d_in, const int* in_sizes, int n_in,
                              void* d_out, int out_size, void* d_ws, size_t ws_size,
                              hipStream_t stream) {
    const float* x_p = (const float*)d_in[0];
    const float* x_f = (const float*)d_in[1];
    const float* x_n = (const float*)d_in[2];
    const float* p1_Ws = (const float*)d_in[3];  const float* p1_bs = (const float*)d_in[4];
    const float* p1_Wr = (const float*)d_in[5];  const float* p1_br = (const float*)d_in[6];
    const float* p2_Ws = (const float*)d_in[7];  const float* p2_bs = (const float*)d_in[8];
    const float* p2_Wr = (const float*)d_in[9];  const float* p2_br = (const float*)d_in[10];
    const float* f1_Ws = (const float*)d_in[11]; const float* f1_bs = (const float*)d_in[12];
    const float* f1_Wr = (const float*)d_in[13]; const float* f1_br = (const float*)d_in[14];
    const float* f2_Ws = (const float*)d_in[15]; const float* f2_bs = (const float*)d_in[16];
    const float* f2_Wr = (const float*)d_in[17]; const float* f2_br = (const float*)d_in[18];
    const float* n1_Ws = (const float*)d_in[19]; const float* n1_bs = (const float*)d_in[20];
    const float* n1_Wr = (const float*)d_in[21]; const float* n1_br = (const float*)d_in[22];
    const float* n2_Ws = (const float*)d_in[23]; const float* n2_bs = (const float*)d_in[24];
    const float* n2_Wr = (const float*)d_in[25]; const float* n2_br = (const float*)d_in[26];
    const float* gate_W = (const float*)d_in[27]; const float* gate_b = (const float*)d_in[28];
    const float* dec_W1 = (const float*)d_in[29]; const float* dec_b1 = (const float*)d_in[30];
    const float* dec_W2 = (const float*)d_in[31]; const float* dec_b2 = (const float*)d_in[32];
    const int*   adj_rows = (const int*)d_in[33];
    const int*   adj_cols = (const int*)d_in[34];
    const float* adj_vals = (const float*)d_in[35];
    const int*   edge_src = (const int*)d_in[36];
    const int*   edge_dst = (const int*)d_in[37];

    char* ws = (char*)d_ws;
    int*    rp   = (int*)(ws + WS_RP);
    int*    H    = (int*)(ws + WS_HIST);
    int*    bsum = (int*)(ws + WS_BSUM);
    int2*   cse  = (int2*)(ws + WS_CV);
    int2*   tmp  = (int2*)(ws + WS_TMP);
    ushort* xall = (ushort*)(ws + WS_XALL);
    float*  S_p = (float*)(ws + WS_SP);
    float*  S_f = (float*)(ws + WS_SF);
    float*  S_n = (float*)(ws + WS_SN);
    float*  h_p = (float*)(ws + WS_HPR);
    float*  h_f = (float*)(ws + WS_HF);
    float*  h_n = (float*)(ws + WS_HN);
    float*  Ys_p = (float*)(ws + WS_YSP);  ushort* Yr_p = (ushort*)(ws + WS_YRP);
    float*  Ys_f = (float*)(ws + WS_YSF);  ushort* Yr_f = (ushort*)(ws + WS_YRF);
    float*  Ys_n = (float*)(ws + WS_YSN);  ushort* Yr_n = (ushort*)(ws + WS_YRN);
    float*  z   = (float*)(ws + WS_Z);
    float*  out = (float*)d_out;

    // bf16 staging of node features (merged, 384B-stride, zero-padded)
    cast_xall_kernel<<<(N_NODES * 192 + 255) / 256, 256, 0, stream>>>(x_p, x_f, x_n, xall);

    // radix CSR build: hist -> scan -> block-private scatter -> per-bucket sort
    radix_hist_kernel<<<NB, 256, 0, stream>>>(adj_rows, H);
    scan_part_kernel<<<SCB, 256, 0, stream>>>(H, bsum);
    scan_bsum_kernel<<<1, 512, 0, stream>>>(bsum, rp);
    scan_final_kernel<<<SCB, 256, 0, stream>>>(H, bsum);
    radix_scatter_kernel<<<NB, 256, 0, stream>>>(adj_rows, adj_cols, adj_vals, H, tmp);
    bucket_sort_kernel<<<KBK, 256, 0, stream>>>(tmp, H, rp, cse);

    // layer-1 spmm for all 3 views
    spmm1_all_kernel<<<N_NODES / 4, 256, 0, stream>>>(xall, rp, cse, S_p, S_f, S_n);

    // layer-1 GEMMs -> h_v (fp32)
    int g1 = (N_NODES + 63) / 64;
    gemm1_kernel<<<g1, 256, 0, stream>>>(x_p, S_p, p1_Ws, p1_bs, p1_Wr, p1_br, h_p, 62);
    gemm1_kernel<<<g1, 256, 0, stream>>>(x_f, S_f, f1_Ws, f1_bs, f1_Wr, f1_br, h_f, 37);
    gemm1_kernel<<<g1, 256, 0, stream>>>(x_n, S_n, n1_Ws, n1_bs, n1_Wr, n1_br, h_n, 37);

    // layer-2 GEMMs (matmul-first): Yself fp32 + Yrel bf16 per view
    dim3 g2((N_NODES + 127) / 128, 5);
    gemm2_kernel<<<g2, 256, 0, stream>>>(h_p, p2_Ws, p2_Wr, Ys_p, Yr_p);
    gemm2_kernel<<<g2, 256, 0, stream>>>(h_f, f2_Ws, f2_Wr, Ys_f, Yr_f);
    gemm2_kernel<<<g2, 256, 0, stream>>>(h_n, n2_Ws, n2_Wr, Ys_n, Yr_n);

    // spmm2 (all views) + bias + gated fusion -> z
    spmm2z_all_kernel<<<N_NODES / 4, 256, 0, stream>>>(
        Ys_p, Yr_p, Ys_f, Yr_f, Ys_n, Yr_n, rp, cse,
        p2_bs, p2_br, f2_bs, f2_br, n2_bs, n2_br, gate_W, gate_b, z);

    // edge decoder: thread per edge, W1 in LDS
    decoder3_kernel<<<(ED_EDGES + 255) / 256, 256, 0, stream>>>(
        z, edge_src, edge_dst, dec_W1, dec_b1, dec_W2, dec_b2, out);
}

// Round 8
// 1442.300 us; speedup vs baseline: 1.1353x; 1.0803x over previous
//
#include <hip/hip_runtime.h>

#define N_NODES 50000
#define R_REL   4
#define E_NNZ   800000
#define ED_EDGES 200000
#define H_DIM   128
#define L_DIM   64

#define RN_TOTAL (R_REL * N_NODES)    // 200000
#define ETOT     (R_REL * E_NNZ)      // 3,200,000

// ----- radix CSR-build constants -----
#define EPB   8192                    // edges per radix block
#define NB    391                     // ceil(ETOT/EPB)
#define RBK   196                     // row buckets per relation (256 rows each)
#define KBK   (R_REL * RBK)           // 784 total buckets
#define HTOT  (KBK * NB)              // 306,544 histogram entries
#define SCB   300                     // ceil(HTOT/1024) scan blocks
#define MAXB  6144                    // LDS edge capacity per bucket

// ---------------- workspace layout (bytes); budget <= 213,601,536 ----------
#define WS_RP    0u            // (RN+1) int -> 800,256
#define WS_HIST  800256u       // HTOT int -> 2,026,496 (pad)
#define WS_BSUM  2026496u      // 1024 int -> 2,030,592
#define WS_CV    2030592u      // ETOT int2 = 25.6e6 -> 27,630,592   (final cse, persistent)
#define WS_TMP   27630720u     // ETOT int2 = 25.6e6 -> 53,230,720   (bucketed tmp; later h_n)
#define WS_XALL  53230720u     // N*192 ushort = 19.2e6 -> 72,430,720 (later Ys_p)
#define WS_SP    72430720u     // N*248 f32 = 49.6e6 -> 122,030,720  (later h_f, Ys_f)
#define WS_SF    122030720u    // N*148 f32 = 29.6e6 -> 151,630,720  (later Yr_p)
#define WS_SN    151630720u    // N*148 f32 = 29.6e6 -> 181,230,720  (later Yr_f)
#define WS_HPR   181230720u    // N*128 f32 = 25.6e6 -> 206,830,720  (h_p; later Ys_n, z)
#define WS_HN    WS_TMP                    // h_n reuses tmp (dead after bucket_sort)
#define WS_HF    WS_SP                     // h_f reuses S_p (dead after gemm1_p)
#define WS_YSP   WS_XALL                   // 12.8e6 (xall dead after spmm1)
#define WS_YSF   (WS_SP + 25600000u)       // 98,030,720 (S_p tail)
#define WS_YRP   WS_SF                     // 25.6e6 (S_f dead after gemm1_f)
#define WS_YRF   WS_SN                     // 25.6e6 (S_n dead after gemm1_n)
#define WS_YSN   WS_HPR                    // 12.8e6 (h_p dead after gemm2_p)
#define WS_YRN   WS_HF                     // 25.6e6 (h_f dead after gemm2_f)
#define WS_Z     194030720u                // 12.8e6 -> 206,830,720 (h_p tail)

__device__ __forceinline__ ushort f2bf(float f) {
    unsigned u = __float_as_uint(f);
    unsigned r = (u + 0x7fffu + ((u >> 16) & 1u)) >> 16;   // RNE
    return (ushort)r;
}
__device__ __forceinline__ float bf2f(ushort u) {
    return __uint_as_float(((unsigned)u) << 16);
}

// ---------------- bf16 staging: one merged 384B-stride table ----------------
__global__ void cast_xall_kernel(const float* __restrict__ xp, const float* __restrict__ xf,
                                 const float* __restrict__ xn, ushort* __restrict__ xall) {
    int i = blockIdx.x * 256 + threadIdx.x;
    if (i >= N_NODES * 192) return;
    int node = i / 192, k = i - node * 192;
    float v = 0.f;
    if (k < 62) v = xp[node * 62 + k];
    else if (k >= 64 && k < 138) {
        int j = k - 64, d = j >> 1;
        v = (j & 1) ? xn[node * 37 + d] : xf[node * 37 + d];
    }
    xall[i] = f2bf(v);
}

// ---------------- radix CSR build ----------------
__global__ void radix_hist_kernel(const int* __restrict__ rows, int* __restrict__ H) {
    __shared__ int hist[KBK];
    int blk = blockIdx.x, t = threadIdx.x;
    for (int i = t; i < KBK; i += 256) hist[i] = 0;
    __syncthreads();
    int base = blk * EPB;
    #pragma unroll 1
    for (int i = 0; i < EPB / 256; i++) {
        int g = base + i * 256 + t;
        if (g < ETOT) {
            int r = g / E_NNZ;
            atomicAdd(&hist[r * RBK + (rows[g] >> 8)], 1);
        }
    }
    __syncthreads();
    for (int i = t; i < KBK; i += 256) H[i * NB + blk] = hist[i];
}

__global__ void scan_part_kernel(const int* __restrict__ H, int* __restrict__ bsum) {
    __shared__ int red[256];
    int base = blockIdx.x * 1024, t = threadIdx.x;
    int s = 0;
    #pragma unroll
    for (int i = 0; i < 4; i++) {
        int idx = base + i * 256 + t;
        if (idx < HTOT) s += H[idx];
    }
    red[t] = s; __syncthreads();
    for (int d = 128; d > 0; d >>= 1) {
        if (t < d) red[t] += red[t + d];
        __syncthreads();
    }
    if (t == 0) bsum[blockIdx.x] = red[0];
}

__global__ void scan_bsum_kernel(int* __restrict__ bsum, int* __restrict__ rp) {
    __shared__ int sh[512];
    int t = threadIdx.x;
    int v = (t < SCB) ? bsum[t] : 0;
    sh[t] = v; __syncthreads();
    for (int d = 1; d < 512; d <<= 1) {
        int u = (t >= d) ? sh[t - d] : 0;
        __syncthreads();
        sh[t] += u;
        __syncthreads();
    }
    if (t < SCB) bsum[t] = sh[t] - v;
    if (t == 0) rp[RN_TOTAL] = ETOT;
}

__global__ void scan_final_kernel(int* __restrict__ H, const int* __restrict__ bsum) {
    __shared__ int sh[256];
    int base = blockIdx.x * 1024, t = threadIdx.x;
    int c[4]; int s = 0;
    #pragma unroll
    for (int i = 0; i < 4; i++) {
        int idx = base + t * 4 + i;
        c[i] = (idx < HTOT) ? H[idx] : 0;
        s += c[i];
    }
    sh[t] = s; __syncthreads();
    for (int d = 1; d < 256; d <<= 1) {
        int u = (t >= d) ? sh[t - d] : 0;
        __syncthreads();
        sh[t] += u;
        __syncthreads();
    }
    int off = bsum[blockIdx.x] + sh[t] - s;
    #pragma unroll
    for (int i = 0; i < 4; i++) {
        int idx = base + t * 4 + i;
        if (idx < HTOT) H[idx] = off;
        off += c[i];
    }
}

__global__ void radix_scatter_kernel(const int* __restrict__ rows, const int* __restrict__ cols,
                                     const float* __restrict__ vals, const int* __restrict__ H,
                                     int2* __restrict__ tmp) {
    __shared__ int cur[KBK];
    int blk = blockIdx.x, t = threadIdx.x;
    for (int i = t; i < KBK; i += 256) cur[i] = H[i * NB + blk];
    __syncthreads();
    int base = blk * EPB;
    #pragma unroll 1
    for (int i = 0; i < EPB / 256; i++) {
        int g = base + i * 256 + t;
        if (g < ETOT) {
            int r = g / E_NNZ;
            int row = rows[g];
            int b = r * RBK + (row >> 8);
            int p = atomicAdd(&cur[b], 1);
            tmp[p] = make_int2(cols[g] | ((row & 255) << 16), __float_as_int(vals[g]));
        }
    }
}

__launch_bounds__(256)
__global__ void bucket_sort_kernel(const int2* __restrict__ tmp, const int* __restrict__ H,
                                   int* __restrict__ rp, int2* __restrict__ cse) {
    __shared__ int hist[256];
    __shared__ int sc[256];
    __shared__ int cur[256];
    __shared__ int2 eb[MAXB];
    int b = blockIdx.x, t = threadIdx.x;
    int start = H[b * NB];
    int end = (b == KBK - 1) ? ETOT : H[(b + 1) * NB];
    int cnt = end - start;
    bool useLds = (cnt <= MAXB);
    hist[t] = 0;
    __syncthreads();
    for (int i = t; i < cnt; i += 256) {
        int2 e = tmp[start + i];
        if (useLds) eb[i] = e;
        atomicAdd(&hist[(e.x >> 16) & 255], 1);
    }
    __syncthreads();
    sc[t] = hist[t]; __syncthreads();
    for (int d = 1; d < 256; d <<= 1) {
        int v = (t >= d) ? sc[t - d] : 0;
        __syncthreads();
        sc[t] += v;
        __syncthreads();
    }
    int pref = sc[t] - hist[t];
    int r = b / RBK, rh = b - r * RBK;
    int grow = rh * 256 + t;
    if (grow < N_NODES) rp[r * N_NODES + grow] = start + pref;
    cur[t] = start + pref;
    __syncthreads();
    for (int i = t; i < cnt; i += 256) {
        int2 e = useLds ? eb[i] : tmp[start + i];
        int rl = (e.x >> 16) & 255;
        int p = atomicAdd(&cur[rl], 1);
        cse[p] = make_int2(e.x & 0xFFFF, e.y);
    }
}

// ---------------- layer-1 spmm, all 3 views, merged table, x4 unroll -------
__global__ void spmm1_all_kernel(const ushort* __restrict__ xall,
                                 const int* __restrict__ rp, const int2* __restrict__ cse,
                                 float* __restrict__ Sp, float* __restrict__ Sf,
                                 float* __restrict__ Sn) {
    int wave = threadIdx.x >> 6, lane = threadIdx.x & 63;
    int row = blockIdx.x * 4 + wave;
    if (row >= N_NODES) return;
    bool lp = lane < 62, lf = lane < 37;
    int opx = lane;
    int ofn = 64 + 2 * lane;
    for (int r = 0; r < R_REL; r++) {
        int e0 = rp[r * N_NODES + row], e1 = rp[r * N_NODES + row + 1];
        float ap = 0.f, af = 0.f, an = 0.f;
        int e = e0;
        for (; e + 4 <= e1; e += 4) {
            int2 q0 = cse[e], q1 = cse[e + 1], q2 = cse[e + 2], q3 = cse[e + 3];
            const ushort* b0 = xall + (size_t)q0.x * 192;
            const ushort* b1 = xall + (size_t)q1.x * 192;
            const ushort* b2 = xall + (size_t)q2.x * 192;
            const ushort* b3 = xall + (size_t)q3.x * 192;
            ushort  p0 = b0[opx], p1 = b1[opx], p2 = b2[opx], p3 = b3[opx];
            ushort2 u0 = *(const ushort2*)&b0[ofn];
            ushort2 u1 = *(const ushort2*)&b1[ofn];
            ushort2 u2 = *(const ushort2*)&b2[ofn];
            ushort2 u3 = *(const ushort2*)&b3[ofn];
            float v0 = __int_as_float(q0.y), v1 = __int_as_float(q1.y);
            float v2 = __int_as_float(q2.y), v3 = __int_as_float(q3.y);
            ap += v0 * bf2f(p0) + v1 * bf2f(p1) + v2 * bf2f(p2) + v3 * bf2f(p3);
            af += v0 * bf2f(u0.x) + v1 * bf2f(u1.x) + v2 * bf2f(u2.x) + v3 * bf2f(u3.x);
            an += v0 * bf2f(u0.y) + v1 * bf2f(u1.y) + v2 * bf2f(u2.y) + v3 * bf2f(u3.y);
        }
        for (; e < e1; e++) {
            int2 q = cse[e];
            const ushort* b = xall + (size_t)q.x * 192;
            float v = __int_as_float(q.y);
            ap += v * bf2f(b[opx]);
            ushort2 u = *(const ushort2*)&b[ofn];
            af += v * bf2f(u.x);
            an += v * bf2f(u.y);
        }
        if (lp) Sp[row * 248 + r * 62 + lane] = ap;
        if (lf) { Sf[row * 148 + r * 37 + lane] = af; Sn[row * 148 + r * 37 + lane] = an; }
    }
}

// ---------------- GEMM1 ----------------
__launch_bounds__(256)
__global__ void gemm1_kernel(const float* __restrict__ x, const float* __restrict__ S,
                             const float* __restrict__ Ws, const float* __restrict__ bs,
                             const float* __restrict__ Wr, const float* __restrict__ br,
                             float* __restrict__ h, int din) {
    __shared__ float sA[64 * 63];
    __shared__ float sW[62 * 132];
    int t = threadIdx.x;
    int i0 = blockIdx.x * 64;
    int rg = t >> 5, cg = t & 31;
    float acc[8][4] = {};
    for (int s = 0; s < 5; s++) {
        const float* Aptr; int astride;
        if (s == 0) { Aptr = x; astride = din; }
        else        { Aptr = S + (s - 1) * din; astride = 4 * din; }
        const float* Wp = (s == 0) ? Ws : (Wr + (s - 1) * H_DIM * din);
        __syncthreads();
        for (int idx = t; idx < 64 * din; idx += 256) {
            int rr = idx / din, k = idx - rr * din;
            int grow = i0 + rr;
            sA[rr * 63 + k] = (grow < N_NODES) ? Aptr[grow * astride + k] : 0.f;
        }
        for (int idx = t; idx < H_DIM * din; idx += 256) {
            int j = idx / din, k = idx - j * din;
            sW[k * 132 + j] = Wp[j * din + k];
        }
        __syncthreads();
        for (int k = 0; k < din; k++) {
            float a[8];
            #pragma unroll
            for (int rr = 0; rr < 8; rr++) a[rr] = sA[(rg * 8 + rr) * 63 + k];
            float4 w = *(const float4*)&sW[k * 132 + cg * 4];
            #pragma unroll
            for (int rr = 0; rr < 8; rr++) {
                acc[rr][0] += a[rr] * w.x; acc[rr][1] += a[rr] * w.y;
                acc[rr][2] += a[rr] * w.z; acc[rr][3] += a[rr] * w.w;
            }
        }
    }
    int j0 = cg * 4;
    float btot[4];
    #pragma unroll
    for (int cc = 0; cc < 4; cc++) {
        float b = bs[j0 + cc];
        #pragma unroll
        for (int r = 0; r < R_REL; r++) b += br[r * H_DIM + j0 + cc];
        btot[cc] = b;
    }
    #pragma unroll
    for (int rr = 0; rr < 8; rr++) {
        int grow = i0 + rg * 8 + rr;
        if (grow < N_NODES) {
            float4 o;
            o.x = fmaxf((acc[rr][0] + btot[0]) * 0.2f, 0.f);
            o.y = fmaxf((acc[rr][1] + btot[1]) * 0.2f, 0.f);
            o.z = fmaxf((acc[rr][2] + btot[2]) * 0.2f, 0.f);
            o.w = fmaxf((acc[rr][3] + btot[3]) * 0.2f, 0.f);
            *(float4*)&h[grow * H_DIM + j0] = o;
        }
    }
}

// ---------------- GEMM2: Yself fp32 (ct=0), Yrel bf16 (ct=1..4) ------------
__launch_bounds__(256)
__global__ void gemm2_kernel(const float* __restrict__ h, const float* __restrict__ Ws2,
                             const float* __restrict__ Wr2, float* __restrict__ Yself,
                             ushort* __restrict__ Yrel) {
    __shared__ float sA[128 * 65];
    __shared__ float sW[64 * 68];
    int t = threadIdx.x;
    int i0 = blockIdx.x * 128;
    int ct = blockIdx.y;
    int rg = t >> 4, cg = t & 15;
    const float* Wp = (ct == 0) ? Ws2 : (Wr2 + (ct - 1) * 64 * H_DIM);
    float acc[8][4] = {};
    for (int kc = 0; kc < 2; kc++) {
        __syncthreads();
        for (int idx = t; idx < 128 * 64; idx += 256) {
            int rr = idx >> 6, k = idx & 63;
            int grow = i0 + rr;
            sA[rr * 65 + k] = (grow < N_NODES) ? h[grow * H_DIM + kc * 64 + k] : 0.f;
        }
        for (int idx = t; idx < 64 * 64; idx += 256) {
            int j = idx >> 6, k = idx & 63;
            sW[k * 68 + j] = Wp[j * H_DIM + kc * 64 + k];
        }
        __syncthreads();
        for (int k = 0; k < 64; k++) {
            float a[8];
            #pragma unroll
            for (int rr = 0; rr < 8; rr++) a[rr] = sA[(rg * 8 + rr) * 65 + k];
            float4 w = *(const float4*)&sW[k * 68 + cg * 4];
            #pragma unroll
            for (int rr = 0; rr < 8; rr++) {
                acc[rr][0] += a[rr] * w.x; acc[rr][1] += a[rr] * w.y;
                acc[rr][2] += a[rr] * w.z; acc[rr][3] += a[rr] * w.w;
            }
        }
    }
    #pragma unroll
    for (int rr = 0; rr < 8; rr++) {
        int grow = i0 + rg * 8 + rr;
        if (grow < N_NODES) {
            if (ct == 0) {
                float4 o = make_float4(acc[rr][0], acc[rr][1], acc[rr][2], acc[rr][3]);
                *(float4*)&Yself[(size_t)grow * 64 + cg * 4] = o;
            } else {
                ushort4 o;
                o.x = f2bf(acc[rr][0]); o.y = f2bf(acc[rr][1]);
                o.z = f2bf(acc[rr][2]); o.w = f2bf(acc[rr][3]);
                *(ushort4*)&Yrel[(size_t)grow * 256 + (ct - 1) * 64 + cg * 4] = o;
            }
        }
    }
}

// ------- spmm2 (all 3 views) + bias + /5 + gated fusion, x4 unroll ---------
__global__ void spmm2z_all_kernel(const float* __restrict__ Ysp, const ushort* __restrict__ Yrp,
                                  const float* __restrict__ Ysf, const ushort* __restrict__ Yrf,
                                  const float* __restrict__ Ysn, const ushort* __restrict__ Yrn,
                                  const int* __restrict__ rp, const int2* __restrict__ cse,
                                  const float* __restrict__ p_bs, const float* __restrict__ p_br,
                                  const float* __restrict__ f_bs, const float* __restrict__ f_br,
                                  const float* __restrict__ n_bs, const float* __restrict__ n_br,
                                  const float* __restrict__ gW, const float* __restrict__ gb,
                                  float* __restrict__ z) {
    int wave = threadIdx.x >> 6, lane = threadIdx.x & 63;
    int row = blockIdx.x * 4 + wave;
    if (row >= N_NODES) return;
    float aP = Ysp[(size_t)row * 64 + lane] + p_bs[lane]
             + p_br[lane] + p_br[64 + lane] + p_br[128 + lane] + p_br[192 + lane];
    float aF = Ysf[(size_t)row * 64 + lane] + f_bs[lane]
             + f_br[lane] + f_br[64 + lane] + f_br[128 + lane] + f_br[192 + lane];
    float aN = Ysn[(size_t)row * 64 + lane] + n_bs[lane]
             + n_br[lane] + n_br[64 + lane] + n_br[128 + lane] + n_br[192 + lane];
    for (int r = 0; r < R_REL; r++) {
        int e0 = rp[r * N_NODES + row], e1 = rp[r * N_NODES + row + 1];
        const ushort* yp = Yrp + r * 64 + lane;
        const ushort* yf = Yrf + r * 64 + lane;
        const ushort* yn = Yrn + r * 64 + lane;
        int e = e0;
        for (; e + 4 <= e1; e += 4) {
            int2 q0 = cse[e], q1 = cse[e + 1], q2 = cse[e + 2], q3 = cse[e + 3];
            size_t o0 = (size_t)q0.x * 256, o1 = (size_t)q1.x * 256;
            size_t o2 = (size_t)q2.x * 256, o3 = (size_t)q3.x * 256;
            float pp0 = bf2f(yp[o0]), pp1 = bf2f(yp[o1]), pp2 = bf2f(yp[o2]), pp3 = bf2f(yp[o3]);
            float ff0 = bf2f(yf[o0]), ff1 = bf2f(yf[o1]), ff2 = bf2f(yf[o2]), ff3 = bf2f(yf[o3]);
            float nn0 = bf2f(yn[o0]), nn1 = bf2f(yn[o1]), nn2 = bf2f(yn[o2]), nn3 = bf2f(yn[o3]);
            float v0 = __int_as_float(q0.y), v1 = __int_as_float(q1.y);
            float v2 = __int_as_float(q2.y), v3 = __int_as_float(q3.y);
            aP += v0 * pp0 + v1 * pp1 + v2 * pp2 + v3 * pp3;
            aF += v0 * ff0 + v1 * ff1 + v2 * ff2 + v3 * ff3;
            aN += v0 * nn0 + v1 * nn1 + v2 * nn2 + v3 * nn3;
        }
        for (; e < e1; e++) {
            int2 q = cse[e];
            size_t o = (size_t)q.x * 256;
            float v = __int_as_float(q.y);
            aP += v * bf2f(yp[o]);
            aF += v * bf2f(yf[o]);
            aN += v * bf2f(yn[o]);
        }
    }
    aP *= 0.2f; aF *= 0.2f; aN *= 0.2f;
    float sp = aP * gW[lane], sf = aF * gW[64 + lane], sn = aN * gW[128 + lane];
    #pragma unroll
    for (int d = 32; d >= 1; d >>= 1) {
        sp += __shfl_xor(sp, d);
        sf += __shfl_xor(sf, d);
        sn += __shfl_xor(sn, d);
    }
    sp += gb[0]; sf += gb[1]; sn += gb[2];
    float m = fmaxf(sp, fmaxf(sf, sn));
    float ep = __expf(sp - m), ef = __expf(sf - m), en = __expf(sn - m);
    float inv = 1.f / (ep + ef + en);
    z[row * 64 + lane] = (ep * aP + ef * aF + en * aN) * inv;
}

// -------- decoder: 2 edges per thread, full W1 in LDS (broadcast ds_read) --
// Each 4-ds_read group (wa,wb,wc,wd) now feeds 32 FMAs (2 edges) instead of
// 16, halving the LDS-pipe issue cost per edge (the R7 bottleneck).
__launch_bounds__(256)
__global__ void decoder4_kernel(const float* __restrict__ z, const int* __restrict__ esrc,
                                const int* __restrict__ edst, const float* __restrict__ w1,
                                const float* __restrict__ b1, const float* __restrict__ w2,
                                const float* __restrict__ b2, float* __restrict__ out) {
    __shared__ float sW1[16384];          // 64 KB: rows j of [wa|wb|wc|wd]
    int t = threadIdx.x;
    for (int i = t; i < 4096; i += 256)
        ((float4*)sW1)[i] = ((const float4*)w1)[i];
    __syncthreads();
    int e1 = blockIdx.x * 512 + t;
    int e2 = e1 + 256;
    bool v2 = e2 < ED_EDGES;
    if (e1 >= ED_EDGES) return;
    int s1 = esrc[e1], d1 = edst[e1];
    int s2 = v2 ? esrc[e2] : s1;
    int d2 = v2 ? edst[e2] : d1;
    const float4* zs1 = (const float4*)(z + (size_t)s1 * 64);
    const float4* zd1 = (const float4*)(z + (size_t)d1 * 64);
    const float4* zs2 = (const float4*)(z + (size_t)s2 * 64);
    const float4* zd2 = (const float4*)(z + (size_t)d2 * 64);
    float hid1[64], hid2[64];
    #pragma unroll
    for (int j = 0; j < 64; j++) { hid1[j] = 0.f; hid2[j] = 0.f; }
    #pragma unroll 1
    for (int kc = 0; kc < 16; kc++) {
        float4 a1 = zs1[kc], b1v4 = zd1[kc];
        float4 a2 = zs2[kc], b2v4 = zd2[kc];
        float4 p1, q1, p2, q2;
        p1.x = a1.x * b1v4.x; q1.x = fabsf(a1.x - b1v4.x);
        p1.y = a1.y * b1v4.y; q1.y = fabsf(a1.y - b1v4.y);
        p1.z = a1.z * b1v4.z; q1.z = fabsf(a1.z - b1v4.z);
        p1.w = a1.w * b1v4.w; q1.w = fabsf(a1.w - b1v4.w);
        p2.x = a2.x * b2v4.x; q2.x = fabsf(a2.x - b2v4.x);
        p2.y = a2.y * b2v4.y; q2.y = fabsf(a2.y - b2v4.y);
        p2.z = a2.z * b2v4.z; q2.z = fabsf(a2.z - b2v4.z);
        p2.w = a2.w * b2v4.w; q2.w = fabsf(a2.w - b2v4.w);
        const float* wb0 = sW1 + kc * 4;
        #pragma unroll
        for (int j = 0; j < 64; j++) {
            const float* wr = wb0 + j * 256;
            float4 wa = *(const float4*)(wr);          // broadcast ds_read_b128
            float4 wbv = *(const float4*)(wr + 64);
            float4 wc = *(const float4*)(wr + 128);
            float4 wd = *(const float4*)(wr + 192);
            hid1[j] += a1.x * wa.x + a1.y * wa.y + a1.z * wa.z + a1.w * wa.w
                     + b1v4.x * wbv.x + b1v4.y * wbv.y + b1v4.z * wbv.z + b1v4.w * wbv.w
                     + p1.x * wc.x + p1.y * wc.y + p1.z * wc.z + p1.w * wc.w
                     + q1.x * wd.x + q1.y * wd.y + q1.z * wd.z + q1.w * wd.w;
            hid2[j] += a2.x * wa.x + a2.y * wa.y + a2.z * wa.z + a2.w * wa.w
                     + b2v4.x * wbv.x + b2v4.y * wbv.y + b2v4.z * wbv.z + b2v4.w * wbv.w
                     + p2.x * wc.x + p2.y * wc.y + p2.z * wc.z + p2.w * wc.w
                     + q2.x * wd.x + q2.y * wd.y + q2.z * wd.z + q2.w * wd.w;
        }
    }
    float lg1 = b2[0], lg2 = b2[0];
    #pragma unroll
    for (int j = 0; j < 64; j++) {
        float bj = b1[j], wj = w2[j];                  // uniform s_loads
        lg1 += fmaxf(hid1[j] + bj, 0.f) * wj;
        lg2 += fmaxf(hid2[j] + bj, 0.f) * wj;
    }
    out[e1] = lg1;
    if (v2) out[e2] = lg2;
}

// ---------------- host ----------------
extern "C" void kernel_launch(void* const* d_in, const int* in_sizes, int n_in,
                              void* d_out, int out_size, void* d_ws, size_t ws_size,
                              hipStream_t stream) {
    const float* x_p = (const float*)d_in[0];
    const float* x_f = (const float*)d_in[1];
    const float* x_n = (const float*)d_in[2];
    const float* p1_Ws = (const float*)d_in[3];  const float* p1_bs = (const float*)d_in[4];
    const float* p1_Wr = (const float*)d_in[5];  const float* p1_br = (const float*)d_in[6];
    const float* p2_Ws = (const float*)d_in[7];  const float* p2_bs = (const float*)d_in[8];
    const float* p2_Wr = (const float*)d_in[9];  const float* p2_br = (const float*)d_in[10];
    const float* f1_Ws = (const float*)d_in[11]; const float* f1_bs = (const float*)d_in[12];
    const float* f1_Wr = (const float*)d_in[13]; const float* f1_br = (const float*)d_in[14];
    const float* f2_Ws = (const float*)d_in[15]; const float* f2_bs = (const float*)d_in[16];
    const float* f2_Wr = (const float*)d_in[17]; const float* f2_br = (const float*)d_in[18];
    const float* n1_Ws = (const float*)d_in[19]; const float* n1_bs = (const float*)d_in[20];
    const float* n1_Wr = (const float*)d_in[21]; const float* n1_br = (const float*)d_in[22];
    const float* n2_Ws = (const float*)d_in[23]; const float* n2_bs = (const float*)d_in[24];
    const float* n2_Wr = (const float*)d_in[25]; const float* n2_br = (const float*)d_in[26];
    const float* gate_W = (const float*)d_in[27]; const float* gate_b = (const float*)d_in[28];
    const float* dec_W1 = (const float*)d_in[29]; const float* dec_b1 = (const float*)d_in[30];
    const float* dec_W2 = (const float*)d_in[31]; const float* dec_b2 = (const float*)d_in[32];
    const int*   adj_rows = (const int*)d_in[33];
    const int*   adj_cols = (const int*)d_in[34];
    const float* adj_vals = (const float*)d_in[35];
    const int*   edge_src = (const int*)d_in[36];
    const int*   edge_dst = (const int*)d_in[37];

    char* ws = (char*)d_ws;
    int*    rp   = (int*)(ws + WS_RP);
    int*    H    = (int*)(ws + WS_HIST);
    int*    bsum = (int*)(ws + WS_BSUM);
    int2*   cse  = (int2*)(ws + WS_CV);
    int2*   tmp  = (int2*)(ws + WS_TMP);
    ushort* xall = (ushort*)(ws + WS_XALL);
    float*  S_p = (float*)(ws + WS_SP);
    float*  S_f = (float*)(ws + WS_SF);
    float*  S_n = (float*)(ws + WS_SN);
    float*  h_p = (float*)(ws + WS_HPR);
    float*  h_f = (float*)(ws + WS_HF);
    float*  h_n = (float*)(ws + WS_HN);
    float*  Ys_p = (float*)(ws + WS_YSP);  ushort* Yr_p = (ushort*)(ws + WS_YRP);
    float*  Ys_f = (float*)(ws + WS_YSF);  ushort* Yr_f = (ushort*)(ws + WS_YRF);
    float*  Ys_n = (float*)(ws + WS_YSN);  ushort* Yr_n = (ushort*)(ws + WS_YRN);
    float*  z   = (float*)(ws + WS_Z);
    float*  out = (float*)d_out;

    // bf16 staging of node features (merged, 384B-stride, zero-padded)
    cast_xall_kernel<<<(N_NODES * 192 + 255) / 256, 256, 0, stream>>>(x_p, x_f, x_n, xall);

    // radix CSR build: hist -> scan -> block-private scatter -> per-bucket sort
    radix_hist_kernel<<<NB, 256, 0, stream>>>(adj_rows, H);
    scan_part_kernel<<<SCB, 256, 0, stream>>>(H, bsum);
    scan_bsum_kernel<<<1, 512, 0, stream>>>(bsum, rp);
    scan_final_kernel<<<SCB, 256, 0, stream>>>(H, bsum);
    radix_scatter_kernel<<<NB, 256, 0, stream>>>(adj_rows, adj_cols, adj_vals, H, tmp);
    bucket_sort_kernel<<<KBK, 256, 0, stream>>>(tmp, H, rp, cse);

    // layer-1 spmm for all 3 views
    spmm1_all_kernel<<<N_NODES / 4, 256, 0, stream>>>(xall, rp, cse, S_p, S_f, S_n);

    // layer-1 GEMMs -> h_v (fp32)
    int g1 = (N_NODES + 63) / 64;
    gemm1_kernel<<<g1, 256, 0, stream>>>(x_p, S_p, p1_Ws, p1_bs, p1_Wr, p1_br, h_p, 62);
    gemm1_kernel<<<g1, 256, 0, stream>>>(x_f, S_f, f1_Ws, f1_bs, f1_Wr, f1_br, h_f, 37);
    gemm1_kernel<<<g1, 256, 0, stream>>>(x_n, S_n, n1_Ws, n1_bs, n1_Wr, n1_br, h_n, 37);

    // layer-2 GEMMs (matmul-first): Yself fp32 + Yrel bf16 per view
    dim3 g2((N_NODES + 127) / 128, 5);
    gemm2_kernel<<<g2, 256, 0, stream>>>(h_p, p2_Ws, p2_Wr, Ys_p, Yr_p);
    gemm2_kernel<<<g2, 256, 0, stream>>>(h_f, f2_Ws, f2_Wr, Ys_f, Yr_f);
    gemm2_kernel<<<g2, 256, 0, stream>>>(h_n, n2_Ws, n2_Wr, Ys_n, Yr_n);

    // spmm2 (all views) + bias + gated fusion -> z
    spmm2z_all_kernel<<<N_NODES / 4, 256, 0, stream>>>(
        Ys_p, Yr_p, Ys_f, Yr_f, Ys_n, Yr_n, rp, cse,
        p2_bs, p2_br, f2_bs, f2_br, n2_bs, n2_br, gate_W, gate_b, z);

    // edge decoder: 2 edges per thread, W1 in LDS
    decoder4_kernel<<<(ED_EDGES + 511) / 512, 256, 0, stream>>>(
        z, edge_src, edge_dst, dec_W1, dec_b1, dec_W2, dec_b2, out);
}

// Round 9
// 1409.845 us; speedup vs baseline: 1.1614x; 1.0230x over previous
//
#include <hip/hip_runtime.h>

#define N_NODES 50000
#define R_REL   4
#define E_NNZ   800000
#define ED_EDGES 200000
#define H_DIM   128
#define L_DIM   64

#define RN_TOTAL (R_REL * N_NODES)    // 200000
#define ETOT     (R_REL * E_NNZ)      // 3,200,000

// ----- radix CSR-build constants -----
#define EPB   8192
#define NB    391
#define RBK   196
#define KBK   (R_REL * RBK)           // 784
#define HTOT  (KBK * NB)              // 306,544
#define SCB   300
#define MAXB  6144

// ---------------- workspace layout (bytes); budget <= 213,601,536 ----------
#define WS_RP    0u
#define WS_HIST  800256u
#define WS_BSUM  2026496u
#define WS_CV    2030592u      // ETOT int2 (final cse, persistent)
#define WS_TMP   27630720u     // ETOT int2 (bucketed tmp; later h_n; later dec partials)
#define WS_XALL  53230720u     // N*192 ushort (later Ys_p)
#define WS_SP    72430720u     // N*248 f32 (later h_f, Ys_f)
#define WS_SF    122030720u    // N*148 f32 (later Yr_p)
#define WS_SN    151630720u    // N*148 f32 (later Yr_f)
#define WS_HPR   181230720u    // N*128 f32 (h_p; later Ys_n, z)
#define WS_HN    WS_TMP
#define WS_HF    WS_SP
#define WS_YSP   WS_XALL
#define WS_YSF   (WS_SP + 25600000u)
#define WS_YRP   WS_SF
#define WS_YRF   WS_SN
#define WS_YSN   WS_HPR
#define WS_YRN   WS_HF
#define WS_Z     194030720u
#define WS_PART  WS_TMP                    // 2*ED f32 = 1.6 MB (tmp/h_n dead)

__device__ __forceinline__ ushort f2bf(float f) {
    unsigned u = __float_as_uint(f);
    unsigned r = (u + 0x7fffu + ((u >> 16) & 1u)) >> 16;   // RNE
    return (ushort)r;
}
__device__ __forceinline__ float bf2f(ushort u) {
    return __uint_as_float(((unsigned)u) << 16);
}

// ---------------- bf16 staging: one merged 384B-stride table ----------------
__global__ void cast_xall_kernel(const float* __restrict__ xp, const float* __restrict__ xf,
                                 const float* __restrict__ xn, ushort* __restrict__ xall) {
    int i = blockIdx.x * 256 + threadIdx.x;
    if (i >= N_NODES * 192) return;
    int node = i / 192, k = i - node * 192;
    float v = 0.f;
    if (k < 62) v = xp[node * 62 + k];
    else if (k >= 64 && k < 138) {
        int j = k - 64, d = j >> 1;
        v = (j & 1) ? xn[node * 37 + d] : xf[node * 37 + d];
    }
    xall[i] = f2bf(v);
}

// ---------------- radix CSR build ----------------
__global__ void radix_hist_kernel(const int* __restrict__ rows, int* __restrict__ H) {
    __shared__ int hist[KBK];
    int blk = blockIdx.x, t = threadIdx.x;
    for (int i = t; i < KBK; i += 256) hist[i] = 0;
    __syncthreads();
    int base = blk * EPB;
    #pragma unroll 1
    for (int i = 0; i < EPB / 256; i++) {
        int g = base + i * 256 + t;
        if (g < ETOT) {
            int r = g / E_NNZ;
            atomicAdd(&hist[r * RBK + (rows[g] >> 8)], 1);
        }
    }
    __syncthreads();
    for (int i = t; i < KBK; i += 256) H[i * NB + blk] = hist[i];
}

__global__ void scan_part_kernel(const int* __restrict__ H, int* __restrict__ bsum) {
    __shared__ int red[256];
    int base = blockIdx.x * 1024, t = threadIdx.x;
    int s = 0;
    #pragma unroll
    for (int i = 0; i < 4; i++) {
        int idx = base + i * 256 + t;
        if (idx < HTOT) s += H[idx];
    }
    red[t] = s; __syncthreads();
    for (int d = 128; d > 0; d >>= 1) {
        if (t < d) red[t] += red[t + d];
        __syncthreads();
    }
    if (t == 0) bsum[blockIdx.x] = red[0];
}

__global__ void scan_bsum_kernel(int* __restrict__ bsum, int* __restrict__ rp) {
    __shared__ int sh[512];
    int t = threadIdx.x;
    int v = (t < SCB) ? bsum[t] : 0;
    sh[t] = v; __syncthreads();
    for (int d = 1; d < 512; d <<= 1) {
        int u = (t >= d) ? sh[t - d] : 0;
        __syncthreads();
        sh[t] += u;
        __syncthreads();
    }
    if (t < SCB) bsum[t] = sh[t] - v;
    if (t == 0) rp[RN_TOTAL] = ETOT;
}

__global__ void scan_final_kernel(int* __restrict__ H, const int* __restrict__ bsum) {
    __shared__ int sh[256];
    int base = blockIdx.x * 1024, t = threadIdx.x;
    int c[4]; int s = 0;
    #pragma unroll
    for (int i = 0; i < 4; i++) {
        int idx = base + t * 4 + i;
        c[i] = (idx < HTOT) ? H[idx] : 0;
        s += c[i];
    }
    sh[t] = s; __syncthreads();
    for (int d = 1; d < 256; d <<= 1) {
        int u = (t >= d) ? sh[t - d] : 0;
        __syncthreads();
        sh[t] += u;
        __syncthreads();
    }
    int off = bsum[blockIdx.x] + sh[t] - s;
    #pragma unroll
    for (int i = 0; i < 4; i++) {
        int idx = base + t * 4 + i;
        if (idx < HTOT) H[idx] = off;
        off += c[i];
    }
}

__global__ void radix_scatter_kernel(const int* __restrict__ rows, const int* __restrict__ cols,
                                     const float* __restrict__ vals, const int* __restrict__ H,
                                     int2* __restrict__ tmp) {
    __shared__ int cur[KBK];
    int blk = blockIdx.x, t = threadIdx.x;
    for (int i = t; i < KBK; i += 256) cur[i] = H[i * NB + blk];
    __syncthreads();
    int base = blk * EPB;
    #pragma unroll 1
    for (int i = 0; i < EPB / 256; i++) {
        int g = base + i * 256 + t;
        if (g < ETOT) {
            int r = g / E_NNZ;
            int row = rows[g];
            int b = r * RBK + (row >> 8);
            int p = atomicAdd(&cur[b], 1);
            tmp[p] = make_int2(cols[g] | ((row & 255) << 16), __float_as_int(vals[g]));
        }
    }
}

__launch_bounds__(256)
__global__ void bucket_sort_kernel(const int2* __restrict__ tmp, const int* __restrict__ H,
                                   int* __restrict__ rp, int2* __restrict__ cse) {
    __shared__ int hist[256];
    __shared__ int sc[256];
    __shared__ int cur[256];
    __shared__ int2 eb[MAXB];
    int b = blockIdx.x, t = threadIdx.x;
    int start = H[b * NB];
    int end = (b == KBK - 1) ? ETOT : H[(b + 1) * NB];
    int cnt = end - start;
    bool useLds = (cnt <= MAXB);
    hist[t] = 0;
    __syncthreads();
    for (int i = t; i < cnt; i += 256) {
        int2 e = tmp[start + i];
        if (useLds) eb[i] = e;
        atomicAdd(&hist[(e.x >> 16) & 255], 1);
    }
    __syncthreads();
    sc[t] = hist[t]; __syncthreads();
    for (int d = 1; d < 256; d <<= 1) {
        int v = (t >= d) ? sc[t - d] : 0;
        __syncthreads();
        sc[t] += v;
        __syncthreads();
    }
    int pref = sc[t] - hist[t];
    int r = b / RBK, rh = b - r * RBK;
    int grow = rh * 256 + t;
    if (grow < N_NODES) rp[r * N_NODES + grow] = start + pref;
    cur[t] = start + pref;
    __syncthreads();
    for (int i = t; i < cnt; i += 256) {
        int2 e = useLds ? eb[i] : tmp[start + i];
        int rl = (e.x >> 16) & 255;
        int p = atomicAdd(&cur[rl], 1);
        cse[p] = make_int2(e.x & 0xFFFF, e.y);
    }
}

// ---------------- layer-1 spmm, all 3 views, merged table, x4 unroll -------
__global__ void spmm1_all_kernel(const ushort* __restrict__ xall,
                                 const int* __restrict__ rp, const int2* __restrict__ cse,
                                 float* __restrict__ Sp, float* __restrict__ Sf,
                                 float* __restrict__ Sn) {
    int wave = threadIdx.x >> 6, lane = threadIdx.x & 63;
    int row = blockIdx.x * 4 + wave;
    if (row >= N_NODES) return;
    bool lp = lane < 62, lf = lane < 37;
    int opx = lane;
    int ofn = 64 + 2 * lane;
    for (int r = 0; r < R_REL; r++) {
        int e0 = rp[r * N_NODES + row], e1 = rp[r * N_NODES + row + 1];
        float ap = 0.f, af = 0.f, an = 0.f;
        int e = e0;
        for (; e + 4 <= e1; e += 4) {
            int2 q0 = cse[e], q1 = cse[e + 1], q2 = cse[e + 2], q3 = cse[e + 3];
            const ushort* b0 = xall + (size_t)q0.x * 192;
            const ushort* b1 = xall + (size_t)q1.x * 192;
            const ushort* b2 = xall + (size_t)q2.x * 192;
            const ushort* b3 = xall + (size_t)q3.x * 192;
            ushort  p0 = b0[opx], p1 = b1[opx], p2 = b2[opx], p3 = b3[opx];
            ushort2 u0 = *(const ushort2*)&b0[ofn];
            ushort2 u1 = *(const ushort2*)&b1[ofn];
            ushort2 u2 = *(const ushort2*)&b2[ofn];
            ushort2 u3 = *(const ushort2*)&b3[ofn];
            float v0 = __int_as_float(q0.y), v1 = __int_as_float(q1.y);
            float v2 = __int_as_float(q2.y), v3 = __int_as_float(q3.y);
            ap += v0 * bf2f(p0) + v1 * bf2f(p1) + v2 * bf2f(p2) + v3 * bf2f(p3);
            af += v0 * bf2f(u0.x) + v1 * bf2f(u1.x) + v2 * bf2f(u2.x) + v3 * bf2f(u3.x);
            an += v0 * bf2f(u0.y) + v1 * bf2f(u1.y) + v2 * bf2f(u2.y) + v3 * bf2f(u3.y);
        }
        for (; e < e1; e++) {
            int2 q = cse[e];
            const ushort* b = xall + (size_t)q.x * 192;
            float v = __int_as_float(q.y);
            ap += v * bf2f(b[opx]);
            ushort2 u = *(const ushort2*)&b[ofn];
            af += v * bf2f(u.x);
            an += v * bf2f(u.y);
        }
        if (lp) Sp[row * 248 + r * 62 + lane] = ap;
        if (lf) { Sf[row * 148 + r * 37 + lane] = af; Sn[row * 148 + r * 37 + lane] = an; }
    }
}

// ---------------- GEMM1 ----------------
__launch_bounds__(256)
__global__ void gemm1_kernel(const float* __restrict__ x, const float* __restrict__ S,
                             const float* __restrict__ Ws, const float* __restrict__ bs,
                             const float* __restrict__ Wr, const float* __restrict__ br,
                             float* __restrict__ h, int din) {
    __shared__ float sA[64 * 63];
    __shared__ float sW[62 * 132];
    int t = threadIdx.x;
    int i0 = blockIdx.x * 64;
    int rg = t >> 5, cg = t & 31;
    float acc[8][4] = {};
    for (int s = 0; s < 5; s++) {
        const float* Aptr; int astride;
        if (s == 0) { Aptr = x; astride = din; }
        else        { Aptr = S + (s - 1) * din; astride = 4 * din; }
        const float* Wp = (s == 0) ? Ws : (Wr + (s - 1) * H_DIM * din);
        __syncthreads();
        for (int idx = t; idx < 64 * din; idx += 256) {
            int rr = idx / din, k = idx - rr * din;
            int grow = i0 + rr;
            sA[rr * 63 + k] = (grow < N_NODES) ? Aptr[grow * astride + k] : 0.f;
        }
        for (int idx = t; idx < H_DIM * din; idx += 256) {
            int j = idx / din, k = idx - j * din;
            sW[k * 132 + j] = Wp[j * din + k];
        }
        __syncthreads();
        for (int k = 0; k < din; k++) {
            float a[8];
            #pragma unroll
            for (int rr = 0; rr < 8; rr++) a[rr] = sA[(rg * 8 + rr) * 63 + k];
            float4 w = *(const float4*)&sW[k * 132 + cg * 4];
            #pragma unroll
            for (int rr = 0; rr < 8; rr++) {
                acc[rr][0] += a[rr] * w.x; acc[rr][1] += a[rr] * w.y;
                acc[rr][2] += a[rr] * w.z; acc[rr][3] += a[rr] * w.w;
            }
        }
    }
    int j0 = cg * 4;
    float btot[4];
    #pragma unroll
    for (int cc = 0; cc < 4; cc++) {
        float b = bs[j0 + cc];
        #pragma unroll
        for (int r = 0; r < R_REL; r++) b += br[r * H_DIM + j0 + cc];
        btot[cc] = b;
    }
    #pragma unroll
    for (int rr = 0; rr < 8; rr++) {
        int grow = i0 + rg * 8 + rr;
        if (grow < N_NODES) {
            float4 o;
            o.x = fmaxf((acc[rr][0] + btot[0]) * 0.2f, 0.f);
            o.y = fmaxf((acc[rr][1] + btot[1]) * 0.2f, 0.f);
            o.z = fmaxf((acc[rr][2] + btot[2]) * 0.2f, 0.f);
            o.w = fmaxf((acc[rr][3] + btot[3]) * 0.2f, 0.f);
            *(float4*)&h[grow * H_DIM + j0] = o;
        }
    }
}

// ---------------- GEMM2: Yself fp32 (ct=0), Yrel bf16 (ct=1..4) ------------
__launch_bounds__(256)
__global__ void gemm2_kernel(const float* __restrict__ h, const float* __restrict__ Ws2,
                             const float* __restrict__ Wr2, float* __restrict__ Yself,
                             ushort* __restrict__ Yrel) {
    __shared__ float sA[128 * 65];
    __shared__ float sW[64 * 68];
    int t = threadIdx.x;
    int i0 = blockIdx.x * 128;
    int ct = blockIdx.y;
    int rg = t >> 4, cg = t & 15;
    const float* Wp = (ct == 0) ? Ws2 : (Wr2 + (ct - 1) * 64 * H_DIM);
    float acc[8][4] = {};
    for (int kc = 0; kc < 2; kc++) {
        __syncthreads();
        for (int idx = t; idx < 128 * 64; idx += 256) {
            int rr = idx >> 6, k = idx & 63;
            int grow = i0 + rr;
            sA[rr * 65 + k] = (grow < N_NODES) ? h[grow * H_DIM + kc * 64 + k] : 0.f;
        }
        for (int idx = t; idx < 64 * 64; idx += 256) {
            int j = idx >> 6, k = idx & 63;
            sW[k * 68 + j] = Wp[j * H_DIM + kc * 64 + k];
        }
        __syncthreads();
        for (int k = 0; k < 64; k++) {
            float a[8];
            #pragma unroll
            for (int rr = 0; rr < 8; rr++) a[rr] = sA[(rg * 8 + rr) * 65 + k];
            float4 w = *(const float4*)&sW[k * 68 + cg * 4];
            #pragma unroll
            for (int rr = 0; rr < 8; rr++) {
                acc[rr][0] += a[rr] * w.x; acc[rr][1] += a[rr] * w.y;
                acc[rr][2] += a[rr] * w.z; acc[rr][3] += a[rr] * w.w;
            }
        }
    }
    #pragma unroll
    for (int rr = 0; rr < 8; rr++) {
        int grow = i0 + rg * 8 + rr;
        if (grow < N_NODES) {
            if (ct == 0) {
                float4 o = make_float4(acc[rr][0], acc[rr][1], acc[rr][2], acc[rr][3]);
                *(float4*)&Yself[(size_t)grow * 64 + cg * 4] = o;
            } else {
                ushort4 o;
                o.x = f2bf(acc[rr][0]); o.y = f2bf(acc[rr][1]);
                o.z = f2bf(acc[rr][2]); o.w = f2bf(acc[rr][3]);
                *(ushort4*)&Yrel[(size_t)grow * 256 + (ct - 1) * 64 + cg * 4] = o;
            }
        }
    }
}

// ------- spmm2 (all 3 views) + bias + /5 + gated fusion, x4 unroll ---------
__global__ void spmm2z_all_kernel(const float* __restrict__ Ysp, const ushort* __restrict__ Yrp,
                                  const float* __restrict__ Ysf, const ushort* __restrict__ Yrf,
                                  const float* __restrict__ Ysn, const ushort* __restrict__ Yrn,
                                  const int* __restrict__ rp, const int2* __restrict__ cse,
                                  const float* __restrict__ p_bs, const float* __restrict__ p_br,
                                  const float* __restrict__ f_bs, const float* __restrict__ f_br,
                                  const float* __restrict__ n_bs, const float* __restrict__ n_br,
                                  const float* __restrict__ gW, const float* __restrict__ gb,
                                  float* __restrict__ z) {
    int wave = threadIdx.x >> 6, lane = threadIdx.x & 63;
    int row = blockIdx.x * 4 + wave;
    if (row >= N_NODES) return;
    float aP = Ysp[(size_t)row * 64 + lane] + p_bs[lane]
             + p_br[lane] + p_br[64 + lane] + p_br[128 + lane] + p_br[192 + lane];
    float aF = Ysf[(size_t)row * 64 + lane] + f_bs[lane]
             + f_br[lane] + f_br[64 + lane] + f_br[128 + lane] + f_br[192 + lane];
    float aN = Ysn[(size_t)row * 64 + lane] + n_bs[lane]
             + n_br[lane] + n_br[64 + lane] + n_br[128 + lane] + n_br[192 + lane];
    for (int r = 0; r < R_REL; r++) {
        int e0 = rp[r * N_NODES + row], e1 = rp[r * N_NODES + row + 1];
        const ushort* yp = Yrp + r * 64 + lane;
        const ushort* yf = Yrf + r * 64 + lane;
        const ushort* yn = Yrn + r * 64 + lane;
        int e = e0;
        for (; e + 4 <= e1; e += 4) {
            int2 q0 = cse[e], q1 = cse[e + 1], q2 = cse[e + 2], q3 = cse[e + 3];
            size_t o0 = (size_t)q0.x * 256, o1 = (size_t)q1.x * 256;
            size_t o2 = (size_t)q2.x * 256, o3 = (size_t)q3.x * 256;
            float pp0 = bf2f(yp[o0]), pp1 = bf2f(yp[o1]), pp2 = bf2f(yp[o2]), pp3 = bf2f(yp[o3]);
            float ff0 = bf2f(yf[o0]), ff1 = bf2f(yf[o1]), ff2 = bf2f(yf[o2]), ff3 = bf2f(yf[o3]);
            float nn0 = bf2f(yn[o0]), nn1 = bf2f(yn[o1]), nn2 = bf2f(yn[o2]), nn3 = bf2f(yn[o3]);
            float v0 = __int_as_float(q0.y), v1 = __int_as_float(q1.y);
            float v2 = __int_as_float(q2.y), v3 = __int_as_float(q3.y);
            aP += v0 * pp0 + v1 * pp1 + v2 * pp2 + v3 * pp3;
            aF += v0 * ff0 + v1 * ff1 + v2 * ff2 + v3 * ff3;
            aN += v0 * nn0 + v1 * nn1 + v2 * nn2 + v3 * nn3;
        }
        for (; e < e1; e++) {
            int2 q = cse[e];
            size_t o = (size_t)q.x * 256;
            float v = __int_as_float(q.y);
            aP += v * bf2f(yp[o]);
            aF += v * bf2f(yf[o]);
            aN += v * bf2f(yn[o]);
        }
    }
    aP *= 0.2f; aF *= 0.2f; aN *= 0.2f;
    float sp = aP * gW[lane], sf = aF * gW[64 + lane], sn = aN * gW[128 + lane];
    #pragma unroll
    for (int d = 32; d >= 1; d >>= 1) {
        sp += __shfl_xor(sp, d);
        sf += __shfl_xor(sf, d);
        sn += __shfl_xor(sn, d);
    }
    sp += gb[0]; sf += gb[1]; sn += gb[2];
    float m = fmaxf(sp, fmaxf(sf, sn));
    float ep = __expf(sp - m), ef = __expf(sf - m), en = __expf(sn - m);
    float inv = 1.f / (ep + ef + en);
    z[row * 64 + lane] = (ep * aP + ef * aF + en * aN) * inv;
}

// -------- decoder: j-split (32 of 64 hidden units per block), 2 edges/thread
// 32 KB LDS + ~115 VGPR -> ~4 waves/SIMD, 782 blocks (~3/CU): the R8 fix is
// occupancy to overlap the 16-deep FMA chains. Partial logits -> combine.
__launch_bounds__(256)
__global__ void decoder5_kernel(const float* __restrict__ z, const int* __restrict__ esrc,
                                const int* __restrict__ edst, const float* __restrict__ w1,
                                const float* __restrict__ b1, const float* __restrict__ w2,
                                float* __restrict__ part) {
    __shared__ float sW1[8192];           // 32 KB: 32 j-rows of [wa|wb|wc|wd]
    int t = threadIdx.x;
    int jh = blockIdx.y;                  // 0 or 1
    const float* w1h = w1 + jh * 32 * 256;
    for (int i = t; i < 2048; i += 256)
        ((float4*)sW1)[i] = ((const float4*)w1h)[i];
    __syncthreads();
    int e1 = blockIdx.x * 512 + t;
    int e2 = e1 + 256;
    bool v2 = e2 < ED_EDGES;
    if (e1 >= ED_EDGES) return;
    int s1 = esrc[e1], d1 = edst[e1];
    int s2 = v2 ? esrc[e2] : s1;
    int d2 = v2 ? edst[e2] : d1;
    const float4* zs1 = (const float4*)(z + (size_t)s1 * 64);
    const float4* zd1 = (const float4*)(z + (size_t)d1 * 64);
    const float4* zs2 = (const float4*)(z + (size_t)s2 * 64);
    const float4* zd2 = (const float4*)(z + (size_t)d2 * 64);
    float hid1[32], hid2[32];
    #pragma unroll
    for (int j = 0; j < 32; j++) { hid1[j] = 0.f; hid2[j] = 0.f; }
    #pragma unroll 1
    for (int kc = 0; kc < 16; kc++) {
        float4 a1 = zs1[kc], b1v4 = zd1[kc];
        float4 a2 = zs2[kc], b2v4 = zd2[kc];
        float4 p1, q1, p2, q2;
        p1.x = a1.x * b1v4.x; q1.x = fabsf(a1.x - b1v4.x);
        p1.y = a1.y * b1v4.y; q1.y = fabsf(a1.y - b1v4.y);
        p1.z = a1.z * b1v4.z; q1.z = fabsf(a1.z - b1v4.z);
        p1.w = a1.w * b1v4.w; q1.w = fabsf(a1.w - b1v4.w);
        p2.x = a2.x * b2v4.x; q2.x = fabsf(a2.x - b2v4.x);
        p2.y = a2.y * b2v4.y; q2.y = fabsf(a2.y - b2v4.y);
        p2.z = a2.z * b2v4.z; q2.z = fabsf(a2.z - b2v4.z);
        p2.w = a2.w * b2v4.w; q2.w = fabsf(a2.w - b2v4.w);
        const float* wb0 = sW1 + kc * 4;
        #pragma unroll
        for (int j = 0; j < 32; j++) {
            const float* wr = wb0 + j * 256;
            float4 wa = *(const float4*)(wr);          // broadcast ds_read_b128
            float4 wbv = *(const float4*)(wr + 64);
            float4 wc = *(const float4*)(wr + 128);
            float4 wd = *(const float4*)(wr + 192);
            hid1[j] += a1.x * wa.x + a1.y * wa.y + a1.z * wa.z + a1.w * wa.w
                     + b1v4.x * wbv.x + b1v4.y * wbv.y + b1v4.z * wbv.z + b1v4.w * wbv.w
                     + p1.x * wc.x + p1.y * wc.y + p1.z * wc.z + p1.w * wc.w
                     + q1.x * wd.x + q1.y * wd.y + q1.z * wd.z + q1.w * wd.w;
            hid2[j] += a2.x * wa.x + a2.y * wa.y + a2.z * wa.z + a2.w * wa.w
                     + b2v4.x * wbv.x + b2v4.y * wbv.y + b2v4.z * wbv.z + b2v4.w * wbv.w
                     + p2.x * wc.x + p2.y * wc.y + p2.z * wc.z + p2.w * wc.w
                     + q2.x * wd.x + q2.y * wd.y + q2.z * wd.z + q2.w * wd.w;
        }
    }
    float lg1 = 0.f, lg2 = 0.f;
    #pragma unroll
    for (int j = 0; j < 32; j++) {
        int gj = jh * 32 + j;
        float bj = b1[gj], wj = w2[gj];                // uniform s_loads
        lg1 += fmaxf(hid1[j] + bj, 0.f) * wj;
        lg2 += fmaxf(hid2[j] + bj, 0.f) * wj;
    }
    part[(size_t)jh * ED_EDGES + e1] = lg1;
    if (v2) part[(size_t)jh * ED_EDGES + e2] = lg2;
}

__global__ void dec_combine_kernel(const float* __restrict__ part, const float* __restrict__ b2,
                                   float* __restrict__ out) {
    int e = blockIdx.x * 256 + threadIdx.x;
    if (e < ED_EDGES) out[e] = part[e] + part[ED_EDGES + e] + b2[0];
}

// ---------------- host ----------------
extern "C" void kernel_launch(void* const* d_in, const int* in_sizes, int n_in,
                              void* d_out, int out_size, void* d_ws, size_t ws_size,
                              hipStream_t stream) {
    const float* x_p = (const float*)d_in[0];
    const float* x_f = (const float*)d_in[1];
    const float* x_n = (const float*)d_in[2];
    const float* p1_Ws = (const float*)d_in[3];  const float* p1_bs = (const float*)d_in[4];
    const float* p1_Wr = (const float*)d_in[5];  const float* p1_br = (const float*)d_in[6];
    const float* p2_Ws = (const float*)d_in[7];  const float* p2_bs = (const float*)d_in[8];
    const float* p2_Wr = (const float*)d_in[9];  const float* p2_br = (const float*)d_in[10];
    const float* f1_Ws = (const float*)d_in[11]; const float* f1_bs = (const float*)d_in[12];
    const float* f1_Wr = (const float*)d_in[13]; const float* f1_br = (const float*)d_in[14];
    const float* f2_Ws = (const float*)d_in[15]; const float* f2_bs = (const float*)d_in[16];
    const float* f2_Wr = (const float*)d_in[17]; const float* f2_br = (const float*)d_in[18];
    const float* n1_Ws = (const float*)d_in[19]; const float* n1_bs = (const float*)d_in[20];
    const float* n1_Wr = (const float*)d_in[21]; const float* n1_br = (const float*)d_in[22];
    const float* n2_Ws = (const float*)d_in[23]; const float* n2_bs = (const float*)d_in[24];
    const float* n2_Wr = (const float*)d_in[25]; const float* n2_br = (const float*)d_in[26];
    const float* gate_W = (const float*)d_in[27]; const float* gate_b = (const float*)d_in[28];
    const float* dec_W1 = (const float*)d_in[29]; const float* dec_b1 = (const float*)d_in[30];
    const float* dec_W2 = (const float*)d_in[31]; const float* dec_b2 = (const float*)d_in[32];
    const int*   adj_rows = (const int*)d_in[33];
    const int*   adj_cols = (const int*)d_in[34];
    const float* adj_vals = (const float*)d_in[35];
    const int*   edge_src = (const int*)d_in[36];
    const int*   edge_dst = (const int*)d_in[37];

    char* ws = (char*)d_ws;
    int*    rp   = (int*)(ws + WS_RP);
    int*    H    = (int*)(ws + WS_HIST);
    int*    bsum = (int*)(ws + WS_BSUM);
    int2*   cse  = (int2*)(ws + WS_CV);
    int2*   tmp  = (int2*)(ws + WS_TMP);
    ushort* xall = (ushort*)(ws + WS_XALL);
    float*  S_p = (float*)(ws + WS_SP);
    float*  S_f = (float*)(ws + WS_SF);
    float*  S_n = (float*)(ws + WS_SN);
    float*  h_p = (float*)(ws + WS_HPR);
    float*  h_f = (float*)(ws + WS_HF);
    float*  h_n = (float*)(ws + WS_HN);
    float*  Ys_p = (float*)(ws + WS_YSP);  ushort* Yr_p = (ushort*)(ws + WS_YRP);
    float*  Ys_f = (float*)(ws + WS_YSF);  ushort* Yr_f = (ushort*)(ws + WS_YRF);
    float*  Ys_n = (float*)(ws + WS_YSN);  ushort* Yr_n = (ushort*)(ws + WS_YRN);
    float*  z    = (float*)(ws + WS_Z);
    float*  part = (float*)(ws + WS_PART);
    float*  out  = (float*)d_out;

    // bf16 staging of node features (merged, 384B-stride, zero-padded)
    cast_xall_kernel<<<(N_NODES * 192 + 255) / 256, 256, 0, stream>>>(x_p, x_f, x_n, xall);

    // radix CSR build: hist -> scan -> block-private scatter -> per-bucket sort
    radix_hist_kernel<<<NB, 256, 0, stream>>>(adj_rows, H);
    scan_part_kernel<<<SCB, 256, 0, stream>>>(H, bsum);
    scan_bsum_kernel<<<1, 512, 0, stream>>>(bsum, rp);
    scan_final_kernel<<<SCB, 256, 0, stream>>>(H, bsum);
    radix_scatter_kernel<<<NB, 256, 0, stream>>>(adj_rows, adj_cols, adj_vals, H, tmp);
    bucket_sort_kernel<<<KBK, 256, 0, stream>>>(tmp, H, rp, cse);

    // layer-1 spmm for all 3 views
    spmm1_all_kernel<<<N_NODES / 4, 256, 0, stream>>>(xall, rp, cse, S_p, S_f, S_n);

    // layer-1 GEMMs -> h_v (fp32)
    int g1 = (N_NODES + 63) / 64;
    gemm1_kernel<<<g1, 256, 0, stream>>>(x_p, S_p, p1_Ws, p1_bs, p1_Wr, p1_br, h_p, 62);
    gemm1_kernel<<<g1, 256, 0, stream>>>(x_f, S_f, f1_Ws, f1_bs, f1_Wr, f1_br, h_f, 37);
    gemm1_kernel<<<g1, 256, 0, stream>>>(x_n, S_n, n1_Ws, n1_bs, n1_Wr, n1_br, h_n, 37);

    // layer-2 GEMMs (matmul-first): Yself fp32 + Yrel bf16 per view
    dim3 g2((N_NODES + 127) / 128, 5);
    gemm2_kernel<<<g2, 256, 0, stream>>>(h_p, p2_Ws, p2_Wr, Ys_p, Yr_p);
    gemm2_kernel<<<g2, 256, 0, stream>>>(h_f, f2_Ws, f2_Wr, Ys_f, Yr_f);
    gemm2_kernel<<<g2, 256, 0, stream>>>(h_n, n2_Ws, n2_Wr, Ys_n, Yr_n);

    // spmm2 (all views) + bias + gated fusion -> z
    spmm2z_all_kernel<<<N_NODES / 4, 256, 0, stream>>>(
        Ys_p, Yr_p, Ys_f, Yr_f, Ys_n, Yr_n, rp, cse,
        p2_bs, p2_br, f2_bs, f2_br, n2_bs, n2_br, gate_W, gate_b, z);

    // edge decoder: j-split halves -> partials -> combine
    dim3 gd((ED_EDGES + 511) / 512, 2);
    decoder5_kernel<<<gd, 256, 0, stream>>>(
        z, edge_src, edge_dst, dec_W1, dec_b1, dec_W2, part);
    dec_combine_kernel<<<(ED_EDGES + 255) / 256, 256, 0, stream>>>(part, dec_b2, out);
}